// Round 7
// baseline (613.147 us; speedup 1.0000x reference)
//
#include <hip/hip_runtime.h>

typedef unsigned int uint;
typedef unsigned short ushort;
typedef unsigned char uchar;
typedef __attribute__((ext_vector_type(8))) short bf16x8;
typedef __attribute__((ext_vector_type(4))) float f32x4;

#define NN 50000
#define NE 800000
#define NG 64
#define NODE_F 11
#define EDGE_F 14
#define HD 128
#define NL 3
#define BN_EPS 1e-5f

#if defined(__has_builtin)
#if __has_builtin(__builtin_amdgcn_cvt_f32_fp8) && __has_builtin(__builtin_amdgcn_cvt_pk_fp8_f32)
#define HW_FP8 1
#endif
#endif

__device__ __forceinline__ uint bfround(float v) {
    uint b = __float_as_uint(v);
    return (b + 0x7fffu + ((b >> 16) & 1u)) >> 16;
}

#ifndef HW_FP8
// ---- manual OCP e4m3 encode (RNE, clamp 448) + decode, used only if no HW cvt ----
__device__ __forceinline__ uint f8enc(float v) {
    float a = fabsf(v);
    uint s = (__float_as_uint(v) >> 31) << 7;
    if (!(a > 0.f)) return s;
    if (a >= 448.f) return s | 0x7e;
    uint ab = __float_as_uint(a);
    int e = (int)(ab >> 23) - 127;
    uint m = ab & 0x7fffffu;
    if (e < -6) {
        if (e < -10) return s;
        uint full = 0x800000u | m;
        int shift = 14 - e;  // 21..24
        uint q = full >> shift;
        uint rem = full & ((1u << shift) - 1u);
        uint half = 1u << (shift - 1);
        if (rem > half || (rem == half && (q & 1))) q++;
        return s | q;
    }
    uint m3 = m >> 20;
    uint rem = m & 0xfffffu;
    if (rem > 0x80000u || (rem == 0x80000u && (m3 & 1))) {
        m3++;
        if (m3 == 8) { m3 = 0; e++; }
    }
    if (e > 8 || (e == 8 && m3 > 6)) return s | 0x7e;
    return s | ((uint)(e + 7) << 3) | m3;
}
__device__ __forceinline__ float f8dec(uint x) {
    uint e = (x >> 3) & 15u, m = x & 7u;
    float v = (e == 0) ? ldexpf((float)m, -9) : ldexpf((float)(8u + m), (int)e - 10);
    return (x & 0x80u) ? -v : v;
}
#endif

// ------- init: prep weights (blocks 0..447) + node embedding (rest) --------
__global__ __launch_bounds__(256)
void init_kernel(const float* __restrict__ x, const float* __restrict__ nW,
                 const float* __restrict__ nb_, const float* __restrict__ lin1,
                 const float* __restrict__ lin2, const float* __restrict__ proj,
                 float* __restrict__ h, uint* __restrict__ hb,
                 ushort* __restrict__ wb, float* __restrict__ projT)
{
    int bid = blockIdx.x;
    if (bid < 448) {
        int idx = bid * 256 + threadIdx.x;
        if (idx >= 7 * HD * HD) return;
        if (idx < 6 * HD * HD) {
            int m = idx >> 14, e = idx & (HD * HD - 1);
            const float* src = (m < 3) ? (lin1 + m * HD * HD) : (lin2 + (m - 3) * HD * HD);
            wb[idx] = (ushort)bfround(src[e]);
        } else {
            int e = idx - 6 * HD * HD;
            int r = e >> 7, c = e & 127;
            projT[c * HD + r] = proj[r * HD + c];
        }
    } else {
        int idx = (bid - 448) * 256 + threadIdx.x;
        if (idx >= NN * 64) return;
        int node = idx >> 6, cp = idx & 63;
        int c2 = cp * 2;
        const float* xr = x + node * NODE_F;
        const float* w0 = nW + c2 * NODE_F;
        const float* w1 = w0 + NODE_F;
        float a0 = nb_[c2], a1 = nb_[c2 + 1];
#pragma unroll
        for (int f = 0; f < NODE_F; ++f) { float xv = xr[f]; a0 += xv * w0[f]; a1 += xv * w1[f]; }
        *(float2*)&h[(size_t)node * HD + c2] = make_float2(a0, a1);
        hb[idx] = bfround(a0) | (bfround(a1) << 16);
    }
}

// ----------------------------- CSR construction ----------------------------
__global__ __launch_bounds__(256)
void hist_kernel(const int* __restrict__ ei, int* __restrict__ deg)
{
    int e = blockIdx.x * 256 + threadIdx.x;
    if (e < NE) atomicAdd(&deg[ei[NE + e]], 1);
}

__global__ __launch_bounds__(256)
void scan1_kernel(const int* __restrict__ deg, int* __restrict__ incl, int* __restrict__ bsum)
{
    int i = blockIdx.x * 256 + threadIdx.x;
    int v = (i < NN) ? deg[i] : 0;
    int lane = threadIdx.x & 63;
#pragma unroll
    for (int off = 1; off < 64; off <<= 1) {
        int u = __shfl_up(v, off);
        if (lane >= off) v += u;
    }
    __shared__ int wsum[4];
    if (lane == 63) wsum[threadIdx.x >> 6] = v;
    __syncthreads();
    int wid = threadIdx.x >> 6;
    int add = 0;
#pragma unroll
    for (int w = 0; w < 3; ++w) if (w < wid) add += wsum[w];
    v += add;
    if (i < NN) incl[i] = v;
    if (threadIdx.x == 255) bsum[blockIdx.x] = v;
}

__global__ __launch_bounds__(256)
void scan2_kernel(const int* __restrict__ bsum, int* __restrict__ bscan, int nb)
{
    int i = threadIdx.x;
    int v = (i < nb) ? bsum[i] : 0;
    int lane = i & 63;
#pragma unroll
    for (int off = 1; off < 64; off <<= 1) {
        int u = __shfl_up(v, off);
        if (lane >= off) v += u;
    }
    __shared__ int wsum[4];
    if (lane == 63) wsum[i >> 6] = v;
    __syncthreads();
    int wid = i >> 6;
    int add = 0;
#pragma unroll
    for (int w = 0; w < 3; ++w) if (w < wid) add += wsum[w];
    v += add;
    bscan[i] = v;
}

__global__ __launch_bounds__(256)
void scan3_kernel(const int* __restrict__ deg, const int* __restrict__ incl,
                  const int* __restrict__ bscan, int* __restrict__ row_start,
                  int* __restrict__ cursor)
{
    int i = blockIdx.x * 256 + threadIdx.x;
    if (i >= NN) return;
    int b = blockIdx.x;
    int base = (b > 0) ? bscan[b - 1] : 0;
    int rs = base + incl[i] - deg[i];
    row_start[i] = rs;
    cursor[i] = rs;
    if (i == 0) row_start[NN] = NE;
}

__global__ __launch_bounds__(256)
void scatter_kernel(const int* __restrict__ ei, int* __restrict__ cursor,
                    int* __restrict__ srcs, int* __restrict__ eid)
{
    int e = blockIdx.x * 256 + threadIdx.x;
    if (e >= NE) return;
    int s = ei[e], d = ei[NE + e];
    int pos = atomicAdd(&cursor[d], 1);
    srcs[pos] = s;
    eid[pos] = e;
}

// -- one-time: emb[j] = fp8(edge_attr[eid[j]] @ eW^T + eb), dst-sorted order --
// Edge-parallel: 4 waves/block, each wave fully unrolls EPW=4 independent edges.
// eW^T staged in LDS (wts[f][c], 2-way-free bank pattern).
#define EPW 4
__global__ __launch_bounds__(256)
void embed_edges_kernel(const float* __restrict__ ea, const int* __restrict__ eid,
                        const float* __restrict__ eW, const float* __restrict__ eb,
                        uchar* __restrict__ emb)
{
    __shared__ float wts[EDGE_F][HD];   // wts[f][c] = eW[c][f]
    for (int idx = threadIdx.x; idx < EDGE_F * HD; idx += 256) {
        int c = idx / EDGE_F, f = idx % EDGE_F;
        wts[f][c] = eW[idx];
    }
    __syncthreads();
    int lane = threadIdx.x & 63;
    int c2 = lane * 2;
    float2 ebv = *(const float2*)&eb[c2];
    int j0 = (blockIdx.x * 4 + (threadIdx.x >> 6)) * EPW;
    if (j0 >= NE) return;

    int e[EPW];
#pragma unroll
    for (int q = 0; q < EPW; ++q) e[q] = eid[j0 + q];

#pragma unroll
    for (int q = 0; q < EPW; ++q) {
        const float2* er = (const float2*)(ea + (size_t)e[q] * EDGE_F);
        float ax = ebv.x, ay = ebv.y;
#pragma unroll
        for (int f2 = 0; f2 < 7; ++f2) {
            float2 av = er[f2];
            float2 wva = *(const float2*)&wts[2 * f2][c2];
            float2 wvb = *(const float2*)&wts[2 * f2 + 1][c2];
            ax += av.x * wva.x + av.y * wvb.x;
            ay += av.x * wva.y + av.y * wvb.y;
        }
        ushort st;
#ifdef HW_FP8
        uint pk = (uint)__builtin_amdgcn_cvt_pk_fp8_f32(ax, ay, 0, false);
        st = (ushort)(pk & 0xffffu);
#else
        st = (ushort)(f8enc(ax) | (f8enc(ay) << 8));
#endif
        *(ushort*)(emb + (size_t)(j0 + q) * HD + c2) = st;
    }
}

// ------ agg (fp8 emb): zin[n] = h[n] + sum_j relu(hb[src_j] + emb[j]) ------
#ifdef HW_FP8
#define DEC2(EV, EX, EY)                                                    \
    float EX = __builtin_amdgcn_cvt_f32_fp8((int)(EV), 0);                  \
    float EY = __builtin_amdgcn_cvt_f32_fp8((int)(EV), 1);
#else
#define DEC2(EV, EX, EY)                                                    \
    float EX = lut[(EV) & 0xff];                                            \
    float EY = lut[((EV) >> 8) & 0xff];
#endif

#define MSGF(HV, EX, EY)                                                    \
    {                                                                       \
        float hx = __uint_as_float((HV) << 16);                             \
        float hy = __uint_as_float((HV) & 0xffff0000u);                     \
        accx += fmaxf(hx + (EX), 0.f);                                      \
        accy += fmaxf(hy + (EY), 0.f);                                      \
    }

__global__ __launch_bounds__(256)
void agg_emb_kernel(const float* __restrict__ h, const uint* __restrict__ hb,
                    const int* __restrict__ srcs, const int* __restrict__ row_start,
                    const uchar* __restrict__ emb, float* __restrict__ zin)
{
#ifndef HW_FP8
    __shared__ float lut[256];
    lut[threadIdx.x & 255] = f8dec(threadIdx.x & 255);
    __syncthreads();
#endif
    int node = blockIdx.x * 4 + (threadIdx.x >> 6);
    if (node >= NN) return;
    int lane = threadIdx.x & 63;
    int c2 = lane * 2;
    float accx = 0.f, accy = 0.f;
    int beg = __builtin_amdgcn_readfirstlane(row_start[node]);
    int end = __builtin_amdgcn_readfirstlane(row_start[node + 1]);
    int j = beg;
    for (; j + 8 <= end; j += 8) {
        int s[8];
        uint hv[8], ev[8];
#pragma unroll
        for (int q = 0; q < 8; ++q) s[q] = srcs[j + q];
#pragma unroll
        for (int q = 0; q < 8; ++q) {
            hv[q] = hb[(size_t)s[q] * 64 + lane];
            ev[q] = *(const ushort*)(emb + (size_t)(j + q) * HD + c2);
        }
#pragma unroll
        for (int q = 0; q < 8; ++q) { DEC2(ev[q], ex, ey) MSGF(hv[q], ex, ey) }
    }
    for (; j + 4 <= end; j += 4) {
        int s0 = srcs[j], s1 = srcs[j + 1], s2 = srcs[j + 2], s3 = srcs[j + 3];
        uint hv0 = hb[(size_t)s0 * 64 + lane];
        uint hv1 = hb[(size_t)s1 * 64 + lane];
        uint hv2 = hb[(size_t)s2 * 64 + lane];
        uint hv3 = hb[(size_t)s3 * 64 + lane];
        uint ev0 = *(const ushort*)(emb + (size_t)j * HD + c2);
        uint ev1 = *(const ushort*)(emb + (size_t)(j + 1) * HD + c2);
        uint ev2 = *(const ushort*)(emb + (size_t)(j + 2) * HD + c2);
        uint ev3 = *(const ushort*)(emb + (size_t)(j + 3) * HD + c2);
        { DEC2(ev0, ex, ey) MSGF(hv0, ex, ey) }
        { DEC2(ev1, ex, ey) MSGF(hv1, ex, ey) }
        { DEC2(ev2, ex, ey) MSGF(hv2, ex, ey) }
        { DEC2(ev3, ex, ey) MSGF(hv3, ex, ey) }
    }
    for (; j < end; ++j) {
        uint hv0 = hb[(size_t)srcs[j] * 64 + lane];
        uint ev0 = *(const ushort*)(emb + (size_t)j * HD + c2);
        { DEC2(ev0, ex, ey) MSGF(hv0, ex, ey) }
    }
    float2 hn = *(const float2*)&h[(size_t)node * HD + c2];
    *(float2*)&zin[(size_t)node * HD + c2] = make_float2(hn.x + accx, hn.y + accy);
}

// ------ agg (fallback, recompute): proven round-5 path, dst-sorted ea_s ----
#define EMSG(HV, EP)                                                       \
    {                                                                      \
        float ax = bx, ay = by;                                            \
        _Pragma("unroll")                                                  \
        for (int f2 = 0; f2 < 7; ++f2) {                                   \
            float2 av = (EP)[f2];                                          \
            ax += av.x * w0[2 * f2] + av.y * w0[2 * f2 + 1];               \
            ay += av.x * w1[2 * f2] + av.y * w1[2 * f2 + 1];               \
        }                                                                  \
        float hx = __uint_as_float((HV) << 16);                            \
        float hy = __uint_as_float((HV) & 0xffff0000u);                    \
        accx += fmaxf(hx + ax, 0.f);                                       \
        accy += fmaxf(hy + ay, 0.f);                                       \
    }

__global__ __launch_bounds__(256)
void permute_ea_kernel(const float* __restrict__ ea, const int* __restrict__ eid,
                       float* __restrict__ ea_s)
{
    int idx = blockIdx.x * 256 + threadIdx.x;
    if (idx >= NE * 7) return;
    int e = idx / 7, f2 = idx % 7;
    float2 v = *(const float2*)(ea + (size_t)eid[e] * EDGE_F + f2 * 2);
    *(float2*)(ea_s + (size_t)e * EDGE_F + f2 * 2) = v;
}

__global__ __launch_bounds__(256)
void agg_recompute_kernel(const float* __restrict__ h, const uint* __restrict__ hb,
                          const int* __restrict__ srcs, const int* __restrict__ row_start,
                          const float* __restrict__ ea_s, const float* __restrict__ eW,
                          const float* __restrict__ eb, float* __restrict__ zin)
{
    int node = blockIdx.x * 4 + (threadIdx.x >> 6);
    if (node >= NN) return;
    int lane = threadIdx.x & 63;
    int c2 = lane * 2;
    float w0[EDGE_F], w1[EDGE_F];
    {
        const float* p = eW + c2 * EDGE_F;
#pragma unroll
        for (int f = 0; f < EDGE_F; ++f) { w0[f] = p[f]; w1[f] = p[EDGE_F + f]; }
    }
    float bx = eb[c2], by = eb[c2 + 1];
    float accx = 0.f, accy = 0.f;
    int beg = __builtin_amdgcn_readfirstlane(row_start[node]);
    int end = __builtin_amdgcn_readfirstlane(row_start[node + 1]);
    int j = beg;
    for (; j + 4 <= end; j += 4) {
        int s0 = srcs[j], s1 = srcs[j + 1], s2 = srcs[j + 2], s3 = srcs[j + 3];
        uint hv0 = hb[(size_t)s0 * 64 + lane];
        uint hv1 = hb[(size_t)s1 * 64 + lane];
        uint hv2 = hb[(size_t)s2 * 64 + lane];
        uint hv3 = hb[(size_t)s3 * 64 + lane];
        const float2* e0 = (const float2*)(ea_s + (size_t)j * EDGE_F);
        const float2* e1 = e0 + 7;
        const float2* e2 = e0 + 14;
        const float2* e3 = e0 + 21;
        EMSG(hv0, e0); EMSG(hv1, e1); EMSG(hv2, e2); EMSG(hv3, e3);
    }
    for (; j < end; ++j) {
        uint hv0 = hb[(size_t)srcs[j] * 64 + lane];
        const float2* e0 = (const float2*)(ea_s + (size_t)j * EDGE_F);
        EMSG(hv0, e0);
    }
    float2 hn = *(const float2*)&h[(size_t)node * HD + c2];
    *(float2*)&zin[(size_t)node * HD + c2] = make_float2(hn.x + accx, hn.y + accy);
}

// --------- fused layer: h = relu(relu(BN(zin@W1^T+b1))@W2^T+b2) + h --------
__global__ __launch_bounds__(256)
void fused_layer_kernel(const float* __restrict__ zin,
                        const ushort* __restrict__ w1b, const float* __restrict__ b1,
                        const float* __restrict__ gamma, const float* __restrict__ beta,
                        const float* __restrict__ mean, const float* __restrict__ var,
                        const ushort* __restrict__ w2b, const float* __restrict__ b2,
                        float* __restrict__ h, ushort* __restrict__ hb, int n)
{
    __shared__ uint Ahi[64 * 64];  // bf16[64][128], XOR-swizzled; reused for z
    __shared__ uint Alo[64 * 64];
    const int t = threadIdx.x;
    const int nb = blockIdx.x * 64;

    {
        int row = t >> 2;
        int kq = (t & 3) * 32;
        int gn = nb + row;
        uint hiw[16], low[16];
        if (gn < n) {
            const float4* src = (const float4*)(zin + (size_t)gn * HD + kq);
#pragma unroll
            for (int i = 0; i < 8; ++i) {
                float4 v = src[i];
                uint h0 = bfround(v.x), h1 = bfround(v.y), h2 = bfround(v.z), h3 = bfround(v.w);
                float r0 = v.x - __uint_as_float(h0 << 16);
                float r1 = v.y - __uint_as_float(h1 << 16);
                float r2 = v.z - __uint_as_float(h2 << 16);
                float r3 = v.w - __uint_as_float(h3 << 16);
                hiw[2 * i]     = h0 | (h1 << 16);
                hiw[2 * i + 1] = h2 | (h3 << 16);
                low[2 * i]     = bfround(r0) | (bfround(r1) << 16);
                low[2 * i + 1] = bfround(r2) | (bfround(r3) << 16);
            }
        } else {
#pragma unroll
            for (int i = 0; i < 16; ++i) { hiw[i] = 0; low[i] = 0; }
        }
        uint rowbase = row * 256;
#pragma unroll
        for (int i = 0; i < 4; ++i) {
            uint byte = (rowbase + (kq + 8 * i) * 2) ^ ((row & 7) << 4);
            *(uint4*)((char*)Ahi + byte) = make_uint4(hiw[4 * i], hiw[4 * i + 1], hiw[4 * i + 2], hiw[4 * i + 3]);
            *(uint4*)((char*)Alo + byte) = make_uint4(low[4 * i], low[4 * i + 1], low[4 * i + 2], low[4 * i + 3]);
        }
    }

    const int w  = t >> 6, l = t & 63;
    const int lc = l & 15, lk = l >> 4;
    bf16x8 wf1[2][4], wf2[2][4];
#pragma unroll
    for (int ct = 0; ct < 2; ++ct)
#pragma unroll
        for (int ks = 0; ks < 4; ++ks) {
            size_t off = (size_t)(w * 32 + ct * 16 + lc) * HD + ks * 32 + lk * 8;
            wf1[ct][ks] = *(const bf16x8*)(w1b + off);
            wf2[ct][ks] = *(const bf16x8*)(w2b + off);
        }

    __syncthreads();

    f32x4 acc[4][2];
#pragma unroll
    for (int rt = 0; rt < 4; ++rt)
#pragma unroll
        for (int ct = 0; ct < 2; ++ct) acc[rt][ct] = (f32x4){0.f, 0.f, 0.f, 0.f};

#pragma unroll
    for (int ks = 0; ks < 4; ++ks) {
#pragma unroll
        for (int rt = 0; rt < 4; ++rt) {
            int row = rt * 16 + lc;
            uint byte = ((uint)(row * 256 + (ks * 32 + lk * 8) * 2)) ^ ((row & 7) << 4);
            bf16x8 ah = *(const bf16x8*)((char*)Ahi + byte);
            bf16x8 al = *(const bf16x8*)((char*)Alo + byte);
            acc[rt][0] = __builtin_amdgcn_mfma_f32_16x16x32_bf16(ah, wf1[0][ks], acc[rt][0], 0, 0, 0);
            acc[rt][0] = __builtin_amdgcn_mfma_f32_16x16x32_bf16(al, wf1[0][ks], acc[rt][0], 0, 0, 0);
            acc[rt][1] = __builtin_amdgcn_mfma_f32_16x16x32_bf16(ah, wf1[1][ks], acc[rt][1], 0, 0, 0);
            acc[rt][1] = __builtin_amdgcn_mfma_f32_16x16x32_bf16(al, wf1[1][ks], acc[rt][1], 0, 0, 0);
        }
    }

    __syncthreads();

#pragma unroll
    for (int ct = 0; ct < 2; ++ct) {
        int col = w * 32 + ct * 16 + lc;
        float bi = b1[col];
        float scv = gamma[col] * rsqrtf(var[col] + BN_EPS);
        float shv = beta[col] - mean[col] * scv;
#pragma unroll
        for (int rt = 0; rt < 4; ++rt) {
#pragma unroll
            for (int r = 0; r < 4; ++r) {
                int rowl = rt * 16 + lk * 4 + r;
                float v = (acc[rt][ct][r] + bi) * scv + shv;
                v = fmaxf(v, 0.f);
                uint byte = ((uint)(rowl * 256 + col * 2)) ^ ((rowl & 7) << 4);
                *(ushort*)((char*)Ahi + byte) = (ushort)bfround(v);
            }
        }
    }

    __syncthreads();

    f32x4 acc2[4][2];
#pragma unroll
    for (int rt = 0; rt < 4; ++rt)
#pragma unroll
        for (int ct = 0; ct < 2; ++ct) acc2[rt][ct] = (f32x4){0.f, 0.f, 0.f, 0.f};

#pragma unroll
    for (int ks = 0; ks < 4; ++ks) {
#pragma unroll
        for (int rt = 0; rt < 4; ++rt) {
            int row = rt * 16 + lc;
            uint byte = ((uint)(row * 256 + (ks * 32 + lk * 8) * 2)) ^ ((row & 7) << 4);
            bf16x8 az = *(const bf16x8*)((char*)Ahi + byte);
            acc2[rt][0] = __builtin_amdgcn_mfma_f32_16x16x32_bf16(az, wf2[0][ks], acc2[rt][0], 0, 0, 0);
            acc2[rt][1] = __builtin_amdgcn_mfma_f32_16x16x32_bf16(az, wf2[1][ks], acc2[rt][1], 0, 0, 0);
        }
    }

#pragma unroll
    for (int ct = 0; ct < 2; ++ct) {
        int col = w * 32 + ct * 16 + lc;
        float bi = b2[col];
#pragma unroll
        for (int rt = 0; rt < 4; ++rt) {
#pragma unroll
            for (int r = 0; r < 4; ++r) {
                int row = nb + rt * 16 + lk * 4 + r;
                if (row < n) {
                    float v = fmaxf(acc2[rt][ct][r] + bi, 0.f) + h[(size_t)row * HD + col];
                    h[(size_t)row * HD + col] = v;
                    hb[(size_t)row * HD + col] = (ushort)bfround(v);
                }
            }
        }
    }
}

// -------- pooling: sorted batch_idx -> chunked local sums, rare atomics ----
__global__ __launch_bounds__(128)
void pool_kernel(const float* __restrict__ h, const int* __restrict__ batch,
                 float* __restrict__ pooled, int* __restrict__ counts, int n, int chunk)
{
    int c = threadIdx.x;
    int n_start = blockIdx.x * chunk;
    if (n_start >= n) return;
    int n_end = min(n_start + chunk, n);
    float local = 0.f;
    int cnt = 0;
    int g_cur = batch[n_start];
    for (int nd = n_start; nd < n_end; ++nd) {
        int g = batch[nd];
        if (g != g_cur) {
            atomicAdd(&pooled[g_cur * HD + c], local);
            if (c == 0) atomicAdd(&counts[g_cur], cnt);
            local = 0.f; cnt = 0; g_cur = g;
        }
        local += h[(size_t)nd * HD + c];
        cnt++;
    }
    atomicAdd(&pooled[g_cur * HD + c], local);
    if (c == 0) atomicAdd(&counts[g_cur], cnt);
}

__global__ __launch_bounds__(128)
void final_kernel(const float* __restrict__ pooled, const int* __restrict__ counts,
                  const float* __restrict__ projT, const float* __restrict__ pb,
                  float* __restrict__ out)
{
    __shared__ float p_lds[HD];
    int g = blockIdx.x, p = threadIdx.x;
    float inv = 1.f / fmaxf((float)counts[g], 1.f);
    p_lds[p] = pooled[g * HD + p];
    __syncthreads();
    float acc = 0.f;
#pragma unroll 4
    for (int c = 0; c < HD; ++c) acc += p_lds[c] * projT[c * HD + p];
    out[g * HD + p] = acc * inv + pb[p];
}

extern "C" void kernel_launch(void* const* d_in, const int* in_sizes, int n_in,
                              void* d_out, int out_size, void* d_ws, size_t ws_size,
                              hipStream_t stream)
{
    const float* x        = (const float*)d_in[0];
    const int*   edge_idx = (const int*)d_in[1];
    const float* edge_attr= (const float*)d_in[2];
    const int*   batch    = (const int*)d_in[3];
    const float* node_W   = (const float*)d_in[4];
    const float* node_b   = (const float*)d_in[5];
    const float* edge_W   = (const float*)d_in[6];
    const float* edge_b   = (const float*)d_in[7];
    const float* lin1_b   = (const float*)d_in[9];
    const float* bn_gamma = (const float*)d_in[10];
    const float* bn_beta  = (const float*)d_in[11];
    const float* bn_mean  = (const float*)d_in[12];
    const float* bn_var   = (const float*)d_in[13];
    const float* lin2_b   = (const float*)d_in[15];
    const float* proj_b   = (const float*)d_in[17];

    char* ws = (char*)d_ws;
    float*  h        = (float*) (ws);                  // 25.6 MB
    float*  zin      = (float*) (ws + 25600000);       // 25.6 MB
    uint*   hb       = (uint*)  (ws + 51200000);       // 12.8 MB (packed bf16, 2ch/uint)
    int*    srcs     = (int*)   (ws + 64000000);       // 3.2 MB
    int*    eid      = (int*)   (ws + 67200000);       // 3.2 MB
    ushort* wb       = (ushort*)(ws + 70400000);       // 196,608
    float*  projT    = (float*) (ws + 70600000);       // 65,536
    float*  pooled   = (float*) (ws + 70700000);       // 32,768
    int*    counts   = (int*)   (ws + 70732768);       // 256 (contiguous after pooled)
    int*    deg      = (int*)   (ws + 70740000);       // 200,000
    int*    incl     = (int*)   (ws + 70940000);       // 200,000
    int*    bsum     = (int*)   (ws + 71140000);       // 1,024
    int*    bscan    = (int*)   (ws + 71142048);       // 1,024
    int*    row_start= (int*)   (ws + 71144096);       // 200,064
    int*    cursor   = (int*)   (ws + 71344160);       // 200,000
    // path-specific region at 72 MB:
    uchar*  emb      = (uchar*) (ws + 72000000);       // 102.4 MB fp8 (emb path)
    float*  ea_s     = (float*) (ws + 72000000);       // 44.8 MB (fallback path)
    const bool use_emb = (ws_size >= (size_t)174400000);

    const int NB = (NN + 255) / 256;  // 196

    // --- CSR build (edge_index constant across layers) ---
    hipMemsetAsync(deg, 0, NN * sizeof(int), stream);
    hist_kernel<<<(NE + 255) / 256, 256, 0, stream>>>(edge_idx, deg);
    scan1_kernel<<<NB, 256, 0, stream>>>(deg, incl, bsum);
    scan2_kernel<<<1, 256, 0, stream>>>(bsum, bscan, NB);
    scan3_kernel<<<NB, 256, 0, stream>>>(deg, incl, bscan, row_start, cursor);
    scatter_kernel<<<(NE + 255) / 256, 256, 0, stream>>>(edge_idx, cursor, srcs, eid);

    if (use_emb) {
        embed_edges_kernel<<<NE / (4 * EPW), 256, 0, stream>>>(
            edge_attr, eid, edge_W, edge_b, emb);
    } else {
        permute_ea_kernel<<<(NE * 7 + 255) / 256, 256, 0, stream>>>(edge_attr, eid, ea_s);
    }

    init_kernel<<<448 + (NN * 64 + 255) / 256, 256, 0, stream>>>(
        x, node_W, node_b, (const float*)d_in[8], (const float*)d_in[14],
        (const float*)d_in[16], h, hb, wb, projT);

    for (int i = 0; i < NL; ++i) {
        if (use_emb) {
            agg_emb_kernel<<<(NN + 3) / 4, 256, 0, stream>>>(
                h, hb, srcs, row_start, emb, zin);
        } else {
            agg_recompute_kernel<<<(NN + 3) / 4, 256, 0, stream>>>(
                h, hb, srcs, row_start, ea_s, edge_W, edge_b, zin);
        }
        fused_layer_kernel<<<(NN + 63) / 64, 256, 0, stream>>>(
            zin, wb + (size_t)i * HD * HD, lin1_b + i * HD,
            bn_gamma + i * HD, bn_beta + i * HD, bn_mean + i * HD, bn_var + i * HD,
            wb + (size_t)(3 + i) * HD * HD, lin2_b + i * HD,
            h, (ushort*)hb, NN);
    }

    hipMemsetAsync(pooled, 0, NG * HD * sizeof(float) + NG * sizeof(int) + 4000, stream);
    pool_kernel<<<(NN + 31) / 32, 128, 0, stream>>>(h, batch, pooled, counts, NN, 32);
    final_kernel<<<NG, HD, 0, stream>>>(pooled, counts, projT, proj_b, (float*)d_out);
}

// Round 8
// 571.220 us; speedup vs baseline: 1.0734x; 1.0734x over previous
//
#include <hip/hip_runtime.h>

typedef unsigned int uint;
typedef unsigned short ushort;
typedef unsigned char uchar;
typedef __attribute__((ext_vector_type(8))) short bf16x8;
typedef __attribute__((ext_vector_type(4))) float f32x4;

#define NN 50000
#define NE 800000
#define NG 64
#define NODE_F 11
#define EDGE_F 14
#define HD 128
#define NL 3
#define BN_EPS 1e-5f

#if defined(__has_builtin)
#if __has_builtin(__builtin_amdgcn_cvt_f32_fp8) && __has_builtin(__builtin_amdgcn_cvt_pk_fp8_f32)
#define HW_FP8 1
#endif
#endif

__device__ __forceinline__ uint bfround(float v) {
    uint b = __float_as_uint(v);
    return (b + 0x7fffu + ((b >> 16) & 1u)) >> 16;
}

#ifndef HW_FP8
__device__ __forceinline__ uint f8enc(float v) {
    float a = fabsf(v);
    uint s = (__float_as_uint(v) >> 31) << 7;
    if (!(a > 0.f)) return s;
    if (a >= 448.f) return s | 0x7e;
    uint ab = __float_as_uint(a);
    int e = (int)(ab >> 23) - 127;
    uint m = ab & 0x7fffffu;
    if (e < -6) {
        if (e < -10) return s;
        uint full = 0x800000u | m;
        int shift = 14 - e;
        uint q = full >> shift;
        uint rem = full & ((1u << shift) - 1u);
        uint half = 1u << (shift - 1);
        if (rem > half || (rem == half && (q & 1))) q++;
        return s | q;
    }
    uint m3 = m >> 20;
    uint rem = m & 0xfffffu;
    if (rem > 0x80000u || (rem == 0x80000u && (m3 & 1))) {
        m3++;
        if (m3 == 8) { m3 = 0; e++; }
    }
    if (e > 8 || (e == 8 && m3 > 6)) return s | 0x7e;
    return s | ((uint)(e + 7) << 3) | m3;
}
__device__ __forceinline__ float f8dec(uint x) {
    uint e = (x >> 3) & 15u, m = x & 7u;
    float v = (e == 0) ? ldexpf((float)m, -9) : ldexpf((float)(8u + m), (int)e - 10);
    return (x & 0x80u) ? -v : v;
}
#endif

// ------- init: prep weights (blocks 0..447) + node embedding (rest) --------
__global__ __launch_bounds__(256)
void init_kernel(const float* __restrict__ x, const float* __restrict__ nW,
                 const float* __restrict__ nb_, const float* __restrict__ lin1,
                 const float* __restrict__ lin2, const float* __restrict__ proj,
                 float* __restrict__ h, uint* __restrict__ hb,
                 ushort* __restrict__ wb, float* __restrict__ projT)
{
    int bid = blockIdx.x;
    if (bid < 448) {
        int idx = bid * 256 + threadIdx.x;
        if (idx >= 7 * HD * HD) return;
        if (idx < 6 * HD * HD) {
            int m = idx >> 14, e = idx & (HD * HD - 1);
            const float* src = (m < 3) ? (lin1 + m * HD * HD) : (lin2 + (m - 3) * HD * HD);
            wb[idx] = (ushort)bfround(src[e]);
        } else {
            int e = idx - 6 * HD * HD;
            int r = e >> 7, c = e & 127;
            projT[c * HD + r] = proj[r * HD + c];
        }
    } else {
        int idx = (bid - 448) * 256 + threadIdx.x;
        if (idx >= NN * 64) return;
        int node = idx >> 6, cp = idx & 63;
        int c2 = cp * 2;
        const float* xr = x + node * NODE_F;
        const float* w0 = nW + c2 * NODE_F;
        const float* w1 = w0 + NODE_F;
        float a0 = nb_[c2], a1 = nb_[c2 + 1];
#pragma unroll
        for (int f = 0; f < NODE_F; ++f) { float xv = xr[f]; a0 += xv * w0[f]; a1 += xv * w1[f]; }
        *(float2*)&h[(size_t)node * HD + c2] = make_float2(a0, a1);
        hb[idx] = bfround(a0) | (bfround(a1) << 16);
    }
}

// ----------------------------- CSR construction ----------------------------
__global__ __launch_bounds__(256)
void hist_kernel(const int* __restrict__ ei, int* __restrict__ deg)
{
    int e = blockIdx.x * 256 + threadIdx.x;
    if (e < NE) atomicAdd(&deg[ei[NE + e]], 1);
}

__global__ __launch_bounds__(256)
void scan1_kernel(const int* __restrict__ deg, int* __restrict__ incl, int* __restrict__ bsum)
{
    int i = blockIdx.x * 256 + threadIdx.x;
    int v = (i < NN) ? deg[i] : 0;
    int lane = threadIdx.x & 63;
#pragma unroll
    for (int off = 1; off < 64; off <<= 1) {
        int u = __shfl_up(v, off);
        if (lane >= off) v += u;
    }
    __shared__ int wsum[4];
    if (lane == 63) wsum[threadIdx.x >> 6] = v;
    __syncthreads();
    int wid = threadIdx.x >> 6;
    int add = 0;
#pragma unroll
    for (int w = 0; w < 3; ++w) if (w < wid) add += wsum[w];
    v += add;
    if (i < NN) incl[i] = v;
    if (threadIdx.x == 255) bsum[blockIdx.x] = v;
}

__global__ __launch_bounds__(256)
void scan2_kernel(const int* __restrict__ bsum, int* __restrict__ bscan, int nb)
{
    int i = threadIdx.x;
    int v = (i < nb) ? bsum[i] : 0;
    int lane = i & 63;
#pragma unroll
    for (int off = 1; off < 64; off <<= 1) {
        int u = __shfl_up(v, off);
        if (lane >= off) v += u;
    }
    __shared__ int wsum[4];
    if (lane == 63) wsum[i >> 6] = v;
    __syncthreads();
    int wid = i >> 6;
    int add = 0;
#pragma unroll
    for (int w = 0; w < 3; ++w) if (w < wid) add += wsum[w];
    v += add;
    bscan[i] = v;
}

__global__ __launch_bounds__(256)
void scan3_kernel(const int* __restrict__ deg, const int* __restrict__ incl,
                  const int* __restrict__ bscan, int* __restrict__ row_start,
                  int* __restrict__ cursor)
{
    int i = blockIdx.x * 256 + threadIdx.x;
    if (i >= NN) return;
    int b = blockIdx.x;
    int base = (b > 0) ? bscan[b - 1] : 0;
    int rs = base + incl[i] - deg[i];
    row_start[i] = rs;
    cursor[i] = rs;
    if (i == 0) row_start[NN] = NE;
}

__global__ __launch_bounds__(256)
void scatter_kernel(const int* __restrict__ ei, int* __restrict__ cursor,
                    int* __restrict__ srcs, int* __restrict__ eid)
{
    int e = blockIdx.x * 256 + threadIdx.x;
    if (e >= NE) return;
    int s = ei[e], d = ei[NE + e];
    int pos = atomicAdd(&cursor[d], 1);
    srcs[pos] = s;
    eid[pos] = e;
}

// -- one-time: emb[j] = fp8(edge_attr[eid[j]] @ eW^T + eb), dst-sorted order --
// Edge-parallel, NO LDS. Per lane: its 2 weight rows = 28 consecutive floats
// (16B-aligned) -> 7 named float4 registers. 4 eids per wave via one int4.
__global__ __launch_bounds__(256)
void embed_edges_kernel(const float* __restrict__ ea, const int* __restrict__ eid,
                        const float* __restrict__ eW, const float* __restrict__ eb,
                        uchar* __restrict__ emb)
{
    int lane = threadIdx.x & 63;
    int c2 = lane * 2;
    // weights: w0[0..13] = q0.xyzw q1.xyzw q2.xyzw q3.xy ; w1[0..13] = q3.zw q4 q5 q6
    const float4* wp = (const float4*)(eW + lane * 28);
    float4 q0 = wp[0], q1 = wp[1], q2 = wp[2], q3 = wp[3], q4 = wp[4], q5 = wp[5], q6 = wp[6];
    float2 ebv = *(const float2*)&eb[c2];

    int j0 = (blockIdx.x * 4 + (threadIdx.x >> 6)) * 4;
    if (j0 >= NE) return;
    int4 e4 = *(const int4*)&eid[j0];
    int e[4] = { e4.x, e4.y, e4.z, e4.w };

    float2 av[4][7];
#pragma unroll
    for (int q = 0; q < 4; ++q) {
        const float2* er = (const float2*)(ea + (size_t)e[q] * EDGE_F);
#pragma unroll
        for (int f2 = 0; f2 < 7; ++f2) av[q][f2] = er[f2];
    }

#pragma unroll
    for (int q = 0; q < 4; ++q) {
        float ax = ebv.x, ay = ebv.y;
        ax += av[q][0].x * q0.x + av[q][0].y * q0.y;
        ax += av[q][1].x * q0.z + av[q][1].y * q0.w;
        ax += av[q][2].x * q1.x + av[q][2].y * q1.y;
        ax += av[q][3].x * q1.z + av[q][3].y * q1.w;
        ax += av[q][4].x * q2.x + av[q][4].y * q2.y;
        ax += av[q][5].x * q2.z + av[q][5].y * q2.w;
        ax += av[q][6].x * q3.x + av[q][6].y * q3.y;
        ay += av[q][0].x * q3.z + av[q][0].y * q3.w;
        ay += av[q][1].x * q4.x + av[q][1].y * q4.y;
        ay += av[q][2].x * q4.z + av[q][2].y * q4.w;
        ay += av[q][3].x * q5.x + av[q][3].y * q5.y;
        ay += av[q][4].x * q5.z + av[q][4].y * q5.w;
        ay += av[q][5].x * q6.x + av[q][5].y * q6.y;
        ay += av[q][6].x * q6.z + av[q][6].y * q6.w;
        ushort st;
#ifdef HW_FP8
        uint pk = (uint)__builtin_amdgcn_cvt_pk_fp8_f32(ax, ay, 0, false);
        st = (ushort)(pk & 0xffffu);
#else
        st = (ushort)(f8enc(ax) | (f8enc(ay) << 8));
#endif
        *(ushort*)(emb + (size_t)(j0 + q) * HD + c2) = st;
    }
}

// ------ agg (fp8 emb): zin[n] = h[n] + sum_j relu(hb[src_j] + emb[j]) ------
#ifdef HW_FP8
#define DEC2(EV, EX, EY)                                                    \
    float EX = __builtin_amdgcn_cvt_f32_fp8((int)(EV), 0);                  \
    float EY = __builtin_amdgcn_cvt_f32_fp8((int)(EV), 1);
#else
#define DEC2(EV, EX, EY)                                                    \
    float EX = lut[(EV) & 0xff];                                            \
    float EY = lut[((EV) >> 8) & 0xff];
#endif

#define MSGF(HV, EX, EY)                                                    \
    {                                                                       \
        float hx = __uint_as_float((HV) << 16);                             \
        float hy = __uint_as_float((HV) & 0xffff0000u);                     \
        accx += fmaxf(hx + (EX), 0.f);                                      \
        accy += fmaxf(hy + (EY), 0.f);                                      \
    }

__global__ __launch_bounds__(256)
void agg_emb_kernel(const float* __restrict__ h, const uint* __restrict__ hb,
                    const int* __restrict__ srcs, const int* __restrict__ row_start,
                    const uchar* __restrict__ emb, float* __restrict__ zin)
{
#ifndef HW_FP8
    __shared__ float lut[256];
    lut[threadIdx.x & 255] = f8dec(threadIdx.x & 255);
    __syncthreads();
#endif
    int node = blockIdx.x * 4 + (threadIdx.x >> 6);
    if (node >= NN) return;
    int lane = threadIdx.x & 63;
    int c2 = lane * 2;
    float accx = 0.f, accy = 0.f;
    int beg = __builtin_amdgcn_readfirstlane(row_start[node]);
    int end = __builtin_amdgcn_readfirstlane(row_start[node + 1]);
    int j = beg;
    for (; j + 8 <= end; j += 8) {
        int s[8];
        uint hv[8], ev[8];
#pragma unroll
        for (int q = 0; q < 8; ++q) s[q] = srcs[j + q];
#pragma unroll
        for (int q = 0; q < 8; ++q) {
            hv[q] = hb[(size_t)s[q] * 64 + lane];
            ev[q] = *(const ushort*)(emb + (size_t)(j + q) * HD + c2);
        }
#pragma unroll
        for (int q = 0; q < 8; ++q) { DEC2(ev[q], ex, ey) MSGF(hv[q], ex, ey) }
    }
    for (; j + 4 <= end; j += 4) {
        int s0 = srcs[j], s1 = srcs[j + 1], s2 = srcs[j + 2], s3 = srcs[j + 3];
        uint hv0 = hb[(size_t)s0 * 64 + lane];
        uint hv1 = hb[(size_t)s1 * 64 + lane];
        uint hv2 = hb[(size_t)s2 * 64 + lane];
        uint hv3 = hb[(size_t)s3 * 64 + lane];
        uint ev0 = *(const ushort*)(emb + (size_t)j * HD + c2);
        uint ev1 = *(const ushort*)(emb + (size_t)(j + 1) * HD + c2);
        uint ev2 = *(const ushort*)(emb + (size_t)(j + 2) * HD + c2);
        uint ev3 = *(const ushort*)(emb + (size_t)(j + 3) * HD + c2);
        { DEC2(ev0, ex, ey) MSGF(hv0, ex, ey) }
        { DEC2(ev1, ex, ey) MSGF(hv1, ex, ey) }
        { DEC2(ev2, ex, ey) MSGF(hv2, ex, ey) }
        { DEC2(ev3, ex, ey) MSGF(hv3, ex, ey) }
    }
    for (; j < end; ++j) {
        uint hv0 = hb[(size_t)srcs[j] * 64 + lane];
        uint ev0 = *(const ushort*)(emb + (size_t)j * HD + c2);
        { DEC2(ev0, ex, ey) MSGF(hv0, ex, ey) }
    }
    float2 hn = *(const float2*)&h[(size_t)node * HD + c2];
    *(float2*)&zin[(size_t)node * HD + c2] = make_float2(hn.x + accx, hn.y + accy);
}

// ------ agg (fallback, recompute): proven round-5 path, dst-sorted ea_s ----
#define EMSG(HV, EP)                                                       \
    {                                                                      \
        float ax = bx, ay = by;                                            \
        _Pragma("unroll")                                                  \
        for (int f2 = 0; f2 < 7; ++f2) {                                   \
            float2 av = (EP)[f2];                                          \
            ax += av.x * w0[2 * f2] + av.y * w0[2 * f2 + 1];               \
            ay += av.x * w1[2 * f2] + av.y * w1[2 * f2 + 1];               \
        }                                                                  \
        float hx = __uint_as_float((HV) << 16);                            \
        float hy = __uint_as_float((HV) & 0xffff0000u);                    \
        accx += fmaxf(hx + ax, 0.f);                                       \
        accy += fmaxf(hy + ay, 0.f);                                       \
    }

__global__ __launch_bounds__(256)
void permute_ea_kernel(const float* __restrict__ ea, const int* __restrict__ eid,
                       float* __restrict__ ea_s)
{
    int idx = blockIdx.x * 256 + threadIdx.x;
    if (idx >= NE * 7) return;
    int e = idx / 7, f2 = idx % 7;
    float2 v = *(const float2*)(ea + (size_t)eid[e] * EDGE_F + f2 * 2);
    *(float2*)(ea_s + (size_t)e * EDGE_F + f2 * 2) = v;
}

__global__ __launch_bounds__(256)
void agg_recompute_kernel(const float* __restrict__ h, const uint* __restrict__ hb,
                          const int* __restrict__ srcs, const int* __restrict__ row_start,
                          const float* __restrict__ ea_s, const float* __restrict__ eW,
                          const float* __restrict__ eb, float* __restrict__ zin)
{
    int node = blockIdx.x * 4 + (threadIdx.x >> 6);
    if (node >= NN) return;
    int lane = threadIdx.x & 63;
    int c2 = lane * 2;
    float w0[EDGE_F], w1[EDGE_F];
    {
        const float* p = eW + c2 * EDGE_F;
#pragma unroll
        for (int f = 0; f < EDGE_F; ++f) { w0[f] = p[f]; w1[f] = p[EDGE_F + f]; }
    }
    float bx = eb[c2], by = eb[c2 + 1];
    float accx = 0.f, accy = 0.f;
    int beg = __builtin_amdgcn_readfirstlane(row_start[node]);
    int end = __builtin_amdgcn_readfirstlane(row_start[node + 1]);
    int j = beg;
    for (; j + 4 <= end; j += 4) {
        int s0 = srcs[j], s1 = srcs[j + 1], s2 = srcs[j + 2], s3 = srcs[j + 3];
        uint hv0 = hb[(size_t)s0 * 64 + lane];
        uint hv1 = hb[(size_t)s1 * 64 + lane];
        uint hv2 = hb[(size_t)s2 * 64 + lane];
        uint hv3 = hb[(size_t)s3 * 64 + lane];
        const float2* e0 = (const float2*)(ea_s + (size_t)j * EDGE_F);
        const float2* e1 = e0 + 7;
        const float2* e2 = e0 + 14;
        const float2* e3 = e0 + 21;
        EMSG(hv0, e0); EMSG(hv1, e1); EMSG(hv2, e2); EMSG(hv3, e3);
    }
    for (; j < end; ++j) {
        uint hv0 = hb[(size_t)srcs[j] * 64 + lane];
        const float2* e0 = (const float2*)(ea_s + (size_t)j * EDGE_F);
        EMSG(hv0, e0);
    }
    float2 hn = *(const float2*)&h[(size_t)node * HD + c2];
    *(float2*)&zin[(size_t)node * HD + c2] = make_float2(hn.x + accx, hn.y + accy);
}

// --------- fused layer: h = relu(relu(BN(zin@W1^T+b1))@W2^T+b2) + h --------
__global__ __launch_bounds__(256)
void fused_layer_kernel(const float* __restrict__ zin,
                        const ushort* __restrict__ w1b, const float* __restrict__ b1,
                        const float* __restrict__ gamma, const float* __restrict__ beta,
                        const float* __restrict__ mean, const float* __restrict__ var,
                        const ushort* __restrict__ w2b, const float* __restrict__ b2,
                        float* __restrict__ h, ushort* __restrict__ hb, int n)
{
    __shared__ uint Ahi[64 * 64];  // bf16[64][128], XOR-swizzled; reused for z
    __shared__ uint Alo[64 * 64];
    const int t = threadIdx.x;
    const int nb = blockIdx.x * 64;

    {
        int row = t >> 2;
        int kq = (t & 3) * 32;
        int gn = nb + row;
        uint hiw[16], low[16];
        if (gn < n) {
            const float4* src = (const float4*)(zin + (size_t)gn * HD + kq);
#pragma unroll
            for (int i = 0; i < 8; ++i) {
                float4 v = src[i];
                uint h0 = bfround(v.x), h1 = bfround(v.y), h2 = bfround(v.z), h3 = bfround(v.w);
                float r0 = v.x - __uint_as_float(h0 << 16);
                float r1 = v.y - __uint_as_float(h1 << 16);
                float r2 = v.z - __uint_as_float(h2 << 16);
                float r3 = v.w - __uint_as_float(h3 << 16);
                hiw[2 * i]     = h0 | (h1 << 16);
                hiw[2 * i + 1] = h2 | (h3 << 16);
                low[2 * i]     = bfround(r0) | (bfround(r1) << 16);
                low[2 * i + 1] = bfround(r2) | (bfround(r3) << 16);
            }
        } else {
#pragma unroll
            for (int i = 0; i < 16; ++i) { hiw[i] = 0; low[i] = 0; }
        }
        uint rowbase = row * 256;
#pragma unroll
        for (int i = 0; i < 4; ++i) {
            uint byte = (rowbase + (kq + 8 * i) * 2) ^ ((row & 7) << 4);
            *(uint4*)((char*)Ahi + byte) = make_uint4(hiw[4 * i], hiw[4 * i + 1], hiw[4 * i + 2], hiw[4 * i + 3]);
            *(uint4*)((char*)Alo + byte) = make_uint4(low[4 * i], low[4 * i + 1], low[4 * i + 2], low[4 * i + 3]);
        }
    }

    const int w  = t >> 6, l = t & 63;
    const int lc = l & 15, lk = l >> 4;
    bf16x8 wf1[2][4], wf2[2][4];
#pragma unroll
    for (int ct = 0; ct < 2; ++ct)
#pragma unroll
        for (int ks = 0; ks < 4; ++ks) {
            size_t off = (size_t)(w * 32 + ct * 16 + lc) * HD + ks * 32 + lk * 8;
            wf1[ct][ks] = *(const bf16x8*)(w1b + off);
            wf2[ct][ks] = *(const bf16x8*)(w2b + off);
        }

    __syncthreads();

    f32x4 acc[4][2];
#pragma unroll
    for (int rt = 0; rt < 4; ++rt)
#pragma unroll
        for (int ct = 0; ct < 2; ++ct) acc[rt][ct] = (f32x4){0.f, 0.f, 0.f, 0.f};

#pragma unroll
    for (int ks = 0; ks < 4; ++ks) {
#pragma unroll
        for (int rt = 0; rt < 4; ++rt) {
            int row = rt * 16 + lc;
            uint byte = ((uint)(row * 256 + (ks * 32 + lk * 8) * 2)) ^ ((row & 7) << 4);
            bf16x8 ah = *(const bf16x8*)((char*)Ahi + byte);
            bf16x8 al = *(const bf16x8*)((char*)Alo + byte);
            acc[rt][0] = __builtin_amdgcn_mfma_f32_16x16x32_bf16(ah, wf1[0][ks], acc[rt][0], 0, 0, 0);
            acc[rt][0] = __builtin_amdgcn_mfma_f32_16x16x32_bf16(al, wf1[0][ks], acc[rt][0], 0, 0, 0);
            acc[rt][1] = __builtin_amdgcn_mfma_f32_16x16x32_bf16(ah, wf1[1][ks], acc[rt][1], 0, 0, 0);
            acc[rt][1] = __builtin_amdgcn_mfma_f32_16x16x32_bf16(al, wf1[1][ks], acc[rt][1], 0, 0, 0);
        }
    }

    __syncthreads();

#pragma unroll
    for (int ct = 0; ct < 2; ++ct) {
        int col = w * 32 + ct * 16 + lc;
        float bi = b1[col];
        float scv = gamma[col] * rsqrtf(var[col] + BN_EPS);
        float shv = beta[col] - mean[col] * scv;
#pragma unroll
        for (int rt = 0; rt < 4; ++rt) {
#pragma unroll
            for (int r = 0; r < 4; ++r) {
                int rowl = rt * 16 + lk * 4 + r;
                float v = (acc[rt][ct][r] + bi) * scv + shv;
                v = fmaxf(v, 0.f);
                uint byte = ((uint)(rowl * 256 + col * 2)) ^ ((rowl & 7) << 4);
                *(ushort*)((char*)Ahi + byte) = (ushort)bfround(v);
            }
        }
    }

    __syncthreads();

    f32x4 acc2[4][2];
#pragma unroll
    for (int rt = 0; rt < 4; ++rt)
#pragma unroll
        for (int ct = 0; ct < 2; ++ct) acc2[rt][ct] = (f32x4){0.f, 0.f, 0.f, 0.f};

#pragma unroll
    for (int ks = 0; ks < 4; ++ks) {
#pragma unroll
        for (int rt = 0; rt < 4; ++rt) {
            int row = rt * 16 + lc;
            uint byte = ((uint)(row * 256 + (ks * 32 + lk * 8) * 2)) ^ ((row & 7) << 4);
            bf16x8 az = *(const bf16x8*)((char*)Ahi + byte);
            acc2[rt][0] = __builtin_amdgcn_mfma_f32_16x16x32_bf16(az, wf2[0][ks], acc2[rt][0], 0, 0, 0);
            acc2[rt][1] = __builtin_amdgcn_mfma_f32_16x16x32_bf16(az, wf2[1][ks], acc2[rt][1], 0, 0, 0);
        }
    }

#pragma unroll
    for (int ct = 0; ct < 2; ++ct) {
        int col = w * 32 + ct * 16 + lc;
        float bi = b2[col];
#pragma unroll
        for (int rt = 0; rt < 4; ++rt) {
#pragma unroll
            for (int r = 0; r < 4; ++r) {
                int row = nb + rt * 16 + lk * 4 + r;
                if (row < n) {
                    float v = fmaxf(acc2[rt][ct][r] + bi, 0.f) + h[(size_t)row * HD + col];
                    h[(size_t)row * HD + col] = v;
                    hb[(size_t)row * HD + col] = (ushort)bfround(v);
                }
            }
        }
    }
}

// -------- pooling: sorted batch_idx -> chunked local sums, rare atomics ----
__global__ __launch_bounds__(128)
void pool_kernel(const float* __restrict__ h, const int* __restrict__ batch,
                 float* __restrict__ pooled, int* __restrict__ counts, int n, int chunk)
{
    int c = threadIdx.x;
    int n_start = blockIdx.x * chunk;
    if (n_start >= n) return;
    int n_end = min(n_start + chunk, n);
    float local = 0.f;
    int cnt = 0;
    int g_cur = batch[n_start];
    for (int nd = n_start; nd < n_end; ++nd) {
        int g = batch[nd];
        if (g != g_cur) {
            atomicAdd(&pooled[g_cur * HD + c], local);
            if (c == 0) atomicAdd(&counts[g_cur], cnt);
            local = 0.f; cnt = 0; g_cur = g;
        }
        local += h[(size_t)nd * HD + c];
        cnt++;
    }
    atomicAdd(&pooled[g_cur * HD + c], local);
    if (c == 0) atomicAdd(&counts[g_cur], cnt);
}

__global__ __launch_bounds__(128)
void final_kernel(const float* __restrict__ pooled, const int* __restrict__ counts,
                  const float* __restrict__ projT, const float* __restrict__ pb,
                  float* __restrict__ out)
{
    __shared__ float p_lds[HD];
    int g = blockIdx.x, p = threadIdx.x;
    float inv = 1.f / fmaxf((float)counts[g], 1.f);
    p_lds[p] = pooled[g * HD + p];
    __syncthreads();
    float acc = 0.f;
#pragma unroll 4
    for (int c = 0; c < HD; ++c) acc += p_lds[c] * projT[c * HD + p];
    out[g * HD + p] = acc * inv + pb[p];
}

extern "C" void kernel_launch(void* const* d_in, const int* in_sizes, int n_in,
                              void* d_out, int out_size, void* d_ws, size_t ws_size,
                              hipStream_t stream)
{
    const float* x        = (const float*)d_in[0];
    const int*   edge_idx = (const int*)d_in[1];
    const float* edge_attr= (const float*)d_in[2];
    const int*   batch    = (const int*)d_in[3];
    const float* node_W   = (const float*)d_in[4];
    const float* node_b   = (const float*)d_in[5];
    const float* edge_W   = (const float*)d_in[6];
    const float* edge_b   = (const float*)d_in[7];
    const float* lin1_b   = (const float*)d_in[9];
    const float* bn_gamma = (const float*)d_in[10];
    const float* bn_beta  = (const float*)d_in[11];
    const float* bn_mean  = (const float*)d_in[12];
    const float* bn_var   = (const float*)d_in[13];
    const float* lin2_b   = (const float*)d_in[15];
    const float* proj_b   = (const float*)d_in[17];

    char* ws = (char*)d_ws;
    float*  h        = (float*) (ws);                  // 25.6 MB
    float*  zin      = (float*) (ws + 25600000);       // 25.6 MB
    uint*   hb       = (uint*)  (ws + 51200000);       // 12.8 MB (packed bf16, 2ch/uint)
    int*    srcs     = (int*)   (ws + 64000000);       // 3.2 MB
    int*    eid      = (int*)   (ws + 67200000);       // 3.2 MB
    ushort* wb       = (ushort*)(ws + 70400000);       // 196,608
    float*  projT    = (float*) (ws + 70600000);       // 65,536
    float*  pooled   = (float*) (ws + 70700000);       // 32,768
    int*    counts   = (int*)   (ws + 70732768);       // 256 (contiguous after pooled)
    int*    deg      = (int*)   (ws + 70740000);       // 200,000
    int*    incl     = (int*)   (ws + 70940000);       // 200,000
    int*    bsum     = (int*)   (ws + 71140000);       // 1,024
    int*    bscan    = (int*)   (ws + 71142048);       // 1,024
    int*    row_start= (int*)   (ws + 71144096);       // 200,064
    int*    cursor   = (int*)   (ws + 71344160);       // 200,000
    // path-specific region at 72 MB:
    uchar*  emb      = (uchar*) (ws + 72000000);       // 102.4 MB fp8 (emb path)
    float*  ea_s     = (float*) (ws + 72000000);       // 44.8 MB (fallback path)
    const bool use_emb = (ws_size >= (size_t)174400000);

    const int NB = (NN + 255) / 256;  // 196

    // --- CSR build (edge_index constant across layers) ---
    hipMemsetAsync(deg, 0, NN * sizeof(int), stream);
    hist_kernel<<<(NE + 255) / 256, 256, 0, stream>>>(edge_idx, deg);
    scan1_kernel<<<NB, 256, 0, stream>>>(deg, incl, bsum);
    scan2_kernel<<<1, 256, 0, stream>>>(bsum, bscan, NB);
    scan3_kernel<<<NB, 256, 0, stream>>>(deg, incl, bscan, row_start, cursor);
    scatter_kernel<<<(NE + 255) / 256, 256, 0, stream>>>(edge_idx, cursor, srcs, eid);

    if (use_emb) {
        embed_edges_kernel<<<NE / 16, 256, 0, stream>>>(
            edge_attr, eid, edge_W, edge_b, emb);
    } else {
        permute_ea_kernel<<<(NE * 7 + 255) / 256, 256, 0, stream>>>(edge_attr, eid, ea_s);
    }

    init_kernel<<<448 + (NN * 64 + 255) / 256, 256, 0, stream>>>(
        x, node_W, node_b, (const float*)d_in[8], (const float*)d_in[14],
        (const float*)d_in[16], h, hb, wb, projT);

    for (int i = 0; i < NL; ++i) {
        if (use_emb) {
            agg_emb_kernel<<<(NN + 3) / 4, 256, 0, stream>>>(
                h, hb, srcs, row_start, emb, zin);
        } else {
            agg_recompute_kernel<<<(NN + 3) / 4, 256, 0, stream>>>(
                h, hb, srcs, row_start, ea_s, edge_W, edge_b, zin);
        }
        fused_layer_kernel<<<(NN + 63) / 64, 256, 0, stream>>>(
            zin, wb + (size_t)i * HD * HD, lin1_b + i * HD,
            bn_gamma + i * HD, bn_beta + i * HD, bn_mean + i * HD, bn_var + i * HD,
            wb + (size_t)(3 + i) * HD * HD, lin2_b + i * HD,
            h, (ushort*)hb, NN);
    }

    hipMemsetAsync(pooled, 0, NG * HD * sizeof(float) + NG * sizeof(int) + 4000, stream);
    pool_kernel<<<(NN + 31) / 32, 128, 0, stream>>>(h, batch, pooled, counts, NN, 32);
    final_kernel<<<NG, HD, 0, stream>>>(pooled, counts, projT, proj_b, (float*)d_out);
}

// Round 9
// 472.457 us; speedup vs baseline: 1.2978x; 1.2090x over previous
//
#include <hip/hip_runtime.h>

typedef unsigned int uint;
typedef unsigned short ushort;
typedef unsigned char uchar;
typedef __attribute__((ext_vector_type(8))) short bf16x8;
typedef __attribute__((ext_vector_type(4))) float f32x4;

#define NN 50000
#define NE 800000
#define NG 64
#define NODE_F 11
#define EDGE_F 14
#define HD 128
#define NL 3
#define BN_EPS 1e-5f

#if defined(__has_builtin)
#if __has_builtin(__builtin_amdgcn_cvt_f32_fp8) && __has_builtin(__builtin_amdgcn_cvt_pk_fp8_f32)
#define HW_FP8 1
#endif
#endif

__device__ __forceinline__ uint bfround(float v) {
    uint b = __float_as_uint(v);
    return (b + 0x7fffu + ((b >> 16) & 1u)) >> 16;
}

#ifndef HW_FP8
__device__ __forceinline__ uint f8enc(float v) {
    float a = fabsf(v);
    uint s = (__float_as_uint(v) >> 31) << 7;
    if (!(a > 0.f)) return s;
    if (a >= 448.f) return s | 0x7e;
    uint ab = __float_as_uint(a);
    int e = (int)(ab >> 23) - 127;
    uint m = ab & 0x7fffffu;
    if (e < -6) {
        if (e < -10) return s;
        uint full = 0x800000u | m;
        int shift = 14 - e;
        uint q = full >> shift;
        uint rem = full & ((1u << shift) - 1u);
        uint half = 1u << (shift - 1);
        if (rem > half || (rem == half && (q & 1))) q++;
        return s | q;
    }
    uint m3 = m >> 20;
    uint rem = m & 0xfffffu;
    if (rem > 0x80000u || (rem == 0x80000u && (m3 & 1))) {
        m3++;
        if (m3 == 8) { m3 = 0; e++; }
    }
    if (e > 8 || (e == 8 && m3 > 6)) return s | 0x7e;
    return s | ((uint)(e + 7) << 3) | m3;
}
__device__ __forceinline__ float f8dec(uint x) {
    uint e = (x >> 3) & 15u, m = x & 7u;
    float v = (e == 0) ? ldexpf((float)m, -9) : ldexpf((float)(8u + m), (int)e - 10);
    return (x & 0x80u) ? -v : v;
}
#endif

// ------- init: prep weights (blocks 0..447) + node embedding (rest) --------
__global__ __launch_bounds__(256)
void init_kernel(const float* __restrict__ x, const float* __restrict__ nW,
                 const float* __restrict__ nb_, const float* __restrict__ lin1,
                 const float* __restrict__ lin2, const float* __restrict__ proj,
                 float* __restrict__ h, uint* __restrict__ hb,
                 ushort* __restrict__ wb, float* __restrict__ projT)
{
    int bid = blockIdx.x;
    if (bid < 448) {
        int idx = bid * 256 + threadIdx.x;
        if (idx >= 7 * HD * HD) return;
        if (idx < 6 * HD * HD) {
            int m = idx >> 14, e = idx & (HD * HD - 1);
            const float* src = (m < 3) ? (lin1 + m * HD * HD) : (lin2 + (m - 3) * HD * HD);
            wb[idx] = (ushort)bfround(src[e]);
        } else {
            int e = idx - 6 * HD * HD;
            int r = e >> 7, c = e & 127;
            projT[c * HD + r] = proj[r * HD + c];
        }
    } else {
        int idx = (bid - 448) * 256 + threadIdx.x;
        if (idx >= NN * 64) return;
        int node = idx >> 6, cp = idx & 63;
        int c2 = cp * 2;
        const float* xr = x + node * NODE_F;
        const float* w0 = nW + c2 * NODE_F;
        const float* w1 = w0 + NODE_F;
        float a0 = nb_[c2], a1 = nb_[c2 + 1];
#pragma unroll
        for (int f = 0; f < NODE_F; ++f) { float xv = xr[f]; a0 += xv * w0[f]; a1 += xv * w1[f]; }
        *(float2*)&h[(size_t)node * HD + c2] = make_float2(a0, a1);
        hb[idx] = bfround(a0) | (bfround(a1) << 16);
    }
}

// ----------------------------- CSR construction ----------------------------
__global__ __launch_bounds__(256)
void hist_kernel(const int* __restrict__ ei, int* __restrict__ deg)
{
    int e = blockIdx.x * 256 + threadIdx.x;
    if (e < NE) atomicAdd(&deg[ei[NE + e]], 1);
}

__global__ __launch_bounds__(256)
void scan1_kernel(const int* __restrict__ deg, int* __restrict__ incl, int* __restrict__ bsum)
{
    int i = blockIdx.x * 256 + threadIdx.x;
    int v = (i < NN) ? deg[i] : 0;
    int lane = threadIdx.x & 63;
#pragma unroll
    for (int off = 1; off < 64; off <<= 1) {
        int u = __shfl_up(v, off);
        if (lane >= off) v += u;
    }
    __shared__ int wsum[4];
    if (lane == 63) wsum[threadIdx.x >> 6] = v;
    __syncthreads();
    int wid = threadIdx.x >> 6;
    int add = 0;
#pragma unroll
    for (int w = 0; w < 3; ++w) if (w < wid) add += wsum[w];
    v += add;
    if (i < NN) incl[i] = v;
    if (threadIdx.x == 255) bsum[blockIdx.x] = v;
}

__global__ __launch_bounds__(256)
void scan2_kernel(const int* __restrict__ bsum, int* __restrict__ bscan, int nb)
{
    int i = threadIdx.x;
    int v = (i < nb) ? bsum[i] : 0;
    int lane = i & 63;
#pragma unroll
    for (int off = 1; off < 64; off <<= 1) {
        int u = __shfl_up(v, off);
        if (lane >= off) v += u;
    }
    __shared__ int wsum[4];
    if (lane == 63) wsum[i >> 6] = v;
    __syncthreads();
    int wid = i >> 6;
    int add = 0;
#pragma unroll
    for (int w = 0; w < 3; ++w) if (w < wid) add += wsum[w];
    v += add;
    bscan[i] = v;
}

__global__ __launch_bounds__(256)
void scan3_kernel(const int* __restrict__ deg, const int* __restrict__ incl,
                  const int* __restrict__ bscan, int* __restrict__ row_start,
                  int* __restrict__ cursor)
{
    int i = blockIdx.x * 256 + threadIdx.x;
    if (i >= NN) return;
    int b = blockIdx.x;
    int base = (b > 0) ? bscan[b - 1] : 0;
    int rs = base + incl[i] - deg[i];
    row_start[i] = rs;
    cursor[i] = rs;
    if (i == 0) row_start[NN] = NE;
}

__global__ __launch_bounds__(256)
void scatter_kernel(const int* __restrict__ ei, int* __restrict__ cursor,
                    int* __restrict__ srcs, int* __restrict__ eid)
{
    int e = blockIdx.x * 256 + threadIdx.x;
    if (e >= NE) return;
    int s = ei[e], d = ei[NE + e];
    int pos = atomicAdd(&cursor[d], 1);
    srcs[pos] = s;
    eid[pos] = e;
}

// -- one-time: emb[j] = fp8(edge_attr[eid[j]] @ eW^T + eb), dst-sorted order --
// Block = 128 edges. Phase 1: lane-parallel random gather of ea rows into LDS
// (896 independent float2 loads / block = deep MLP). Phase 2: per-wave compute,
// weights in 7 float4 regs/lane, LDS broadcast reads (conflict-free).
#define EB 128
__global__ __launch_bounds__(256)
void embed_edges_kernel(const float* __restrict__ ea, const int* __restrict__ eid,
                        const float* __restrict__ eW, const float* __restrict__ eb,
                        uchar* __restrict__ emb)
{
    __shared__ int eid_lds[EB];
    __shared__ float tile[EB][EDGE_F];
    const int t = threadIdx.x;
    const int j0 = blockIdx.x * EB;

    if (t < EB) eid_lds[t] = eid[j0 + t];

    int lane = t & 63;
    const float4* wp = (const float4*)(eW + lane * 28);
    float4 q0 = wp[0], q1 = wp[1], q2 = wp[2], q3 = wp[3], q4 = wp[4], q5 = wp[5], q6 = wp[6];
    float2 ebv = *(const float2*)&eb[lane * 2];

    __syncthreads();

    // gather: idx -> (edge el, feature-pair f2); 7 threads per edge row
#pragma unroll
    for (int rep = 0; rep < (EB * 7) / 256; ++rep) {
        int idx = rep * 256 + t;
        int el = idx / 7, f2 = idx % 7;
        float2 v = *(const float2*)(ea + (size_t)eid_lds[el] * EDGE_F + 2 * f2);
        *(float2*)&tile[el][2 * f2] = v;
    }
    // 128*7=896 = 3*256 + 128
    {
        int idx = 768 + t;
        if (idx < EB * 7) {
            int el = idx / 7, f2 = idx % 7;
            float2 v = *(const float2*)(ea + (size_t)eid_lds[el] * EDGE_F + 2 * f2);
            *(float2*)&tile[el][2 * f2] = v;
        }
    }
    __syncthreads();

    const int w = t >> 6;
    const int c2 = lane * 2;
#pragma unroll 4
    for (int el = w * 32; el < w * 32 + 32; ++el) {
        float2 a0 = *(const float2*)&tile[el][0];
        float2 a1 = *(const float2*)&tile[el][2];
        float2 a2 = *(const float2*)&tile[el][4];
        float2 a3 = *(const float2*)&tile[el][6];
        float2 a4 = *(const float2*)&tile[el][8];
        float2 a5 = *(const float2*)&tile[el][10];
        float2 a6 = *(const float2*)&tile[el][12];
        float ax = ebv.x, ay = ebv.y;
        ax += a0.x * q0.x + a0.y * q0.y;
        ax += a1.x * q0.z + a1.y * q0.w;
        ax += a2.x * q1.x + a2.y * q1.y;
        ax += a3.x * q1.z + a3.y * q1.w;
        ax += a4.x * q2.x + a4.y * q2.y;
        ax += a5.x * q2.z + a5.y * q2.w;
        ax += a6.x * q3.x + a6.y * q3.y;
        ay += a0.x * q3.z + a0.y * q3.w;
        ay += a1.x * q4.x + a1.y * q4.y;
        ay += a2.x * q4.z + a2.y * q4.w;
        ay += a3.x * q5.x + a3.y * q5.y;
        ay += a4.x * q5.z + a4.y * q5.w;
        ay += a5.x * q6.x + a5.y * q6.y;
        ay += a6.x * q6.z + a6.y * q6.w;
        ushort st;
#ifdef HW_FP8
        uint pk = (uint)__builtin_amdgcn_cvt_pk_fp8_f32(ax, ay, 0, false);
        st = (ushort)(pk & 0xffffu);
#else
        st = (ushort)(f8enc(ax) | (f8enc(ay) << 8));
#endif
        *(ushort*)(emb + (size_t)(j0 + el) * HD + c2) = st;
    }
}

// ------ agg (fp8 emb): zin[n] = h[n] + sum_j relu(hb[src_j] + emb[j]) ------
#ifdef HW_FP8
#define DEC2(EV, EX, EY)                                                    \
    float EX = __builtin_amdgcn_cvt_f32_fp8((int)(EV), 0);                  \
    float EY = __builtin_amdgcn_cvt_f32_fp8((int)(EV), 1);
#else
#define DEC2(EV, EX, EY)                                                    \
    float EX = lut[(EV) & 0xff];                                            \
    float EY = lut[((EV) >> 8) & 0xff];
#endif

#define MSGF(HV, EX, EY)                                                    \
    {                                                                       \
        float hx = __uint_as_float((HV) << 16);                             \
        float hy = __uint_as_float((HV) & 0xffff0000u);                     \
        accx += fmaxf(hx + (EX), 0.f);                                      \
        accy += fmaxf(hy + (EY), 0.f);                                      \
    }

__global__ __launch_bounds__(256)
void agg_emb_kernel(const float* __restrict__ h, const uint* __restrict__ hb,
                    const int* __restrict__ srcs, const int* __restrict__ row_start,
                    const uchar* __restrict__ emb, float* __restrict__ zin)
{
#ifndef HW_FP8
    __shared__ float lut[256];
    lut[threadIdx.x & 255] = f8dec(threadIdx.x & 255);
    __syncthreads();
#endif
    int node = blockIdx.x * 4 + (threadIdx.x >> 6);
    if (node >= NN) return;
    int lane = threadIdx.x & 63;
    int c2 = lane * 2;
    float accx = 0.f, accy = 0.f;
    int beg = __builtin_amdgcn_readfirstlane(row_start[node]);
    int end = __builtin_amdgcn_readfirstlane(row_start[node + 1]);
    int j = beg;
    for (; j + 8 <= end; j += 8) {
        int s[8];
        uint hv[8], ev[8];
#pragma unroll
        for (int q = 0; q < 8; ++q) s[q] = srcs[j + q];
#pragma unroll
        for (int q = 0; q < 8; ++q) {
            hv[q] = hb[(size_t)s[q] * 64 + lane];
            ev[q] = *(const ushort*)(emb + (size_t)(j + q) * HD + c2);
        }
#pragma unroll
        for (int q = 0; q < 8; ++q) { DEC2(ev[q], ex, ey) MSGF(hv[q], ex, ey) }
    }
    for (; j + 4 <= end; j += 4) {
        int s0 = srcs[j], s1 = srcs[j + 1], s2 = srcs[j + 2], s3 = srcs[j + 3];
        uint hv0 = hb[(size_t)s0 * 64 + lane];
        uint hv1 = hb[(size_t)s1 * 64 + lane];
        uint hv2 = hb[(size_t)s2 * 64 + lane];
        uint hv3 = hb[(size_t)s3 * 64 + lane];
        uint ev0 = *(const ushort*)(emb + (size_t)j * HD + c2);
        uint ev1 = *(const ushort*)(emb + (size_t)(j + 1) * HD + c2);
        uint ev2 = *(const ushort*)(emb + (size_t)(j + 2) * HD + c2);
        uint ev3 = *(const ushort*)(emb + (size_t)(j + 3) * HD + c2);
        { DEC2(ev0, ex, ey) MSGF(hv0, ex, ey) }
        { DEC2(ev1, ex, ey) MSGF(hv1, ex, ey) }
        { DEC2(ev2, ex, ey) MSGF(hv2, ex, ey) }
        { DEC2(ev3, ex, ey) MSGF(hv3, ex, ey) }
    }
    for (; j < end; ++j) {
        uint hv0 = hb[(size_t)srcs[j] * 64 + lane];
        uint ev0 = *(const ushort*)(emb + (size_t)j * HD + c2);
        { DEC2(ev0, ex, ey) MSGF(hv0, ex, ey) }
    }
    float2 hn = *(const float2*)&h[(size_t)node * HD + c2];
    *(float2*)&zin[(size_t)node * HD + c2] = make_float2(hn.x + accx, hn.y + accy);
}

// ------ agg (fallback, recompute): proven round-5 path, dst-sorted ea_s ----
#define EMSG(HV, EP)                                                       \
    {                                                                      \
        float ax = bx, ay = by;                                            \
        _Pragma("unroll")                                                  \
        for (int f2 = 0; f2 < 7; ++f2) {                                   \
            float2 av = (EP)[f2];                                          \
            ax += av.x * w0[2 * f2] + av.y * w0[2 * f2 + 1];               \
            ay += av.x * w1[2 * f2] + av.y * w1[2 * f2 + 1];               \
        }                                                                  \
        float hx = __uint_as_float((HV) << 16);                            \
        float hy = __uint_as_float((HV) & 0xffff0000u);                    \
        accx += fmaxf(hx + ax, 0.f);                                       \
        accy += fmaxf(hy + ay, 0.f);                                       \
    }

__global__ __launch_bounds__(256)
void permute_ea_kernel(const float* __restrict__ ea, const int* __restrict__ eid,
                       float* __restrict__ ea_s)
{
    int idx = blockIdx.x * 256 + threadIdx.x;
    if (idx >= NE * 7) return;
    int e = idx / 7, f2 = idx % 7;
    float2 v = *(const float2*)(ea + (size_t)eid[e] * EDGE_F + f2 * 2);
    *(float2*)(ea_s + (size_t)e * EDGE_F + f2 * 2) = v;
}

__global__ __launch_bounds__(256)
void agg_recompute_kernel(const float* __restrict__ h, const uint* __restrict__ hb,
                          const int* __restrict__ srcs, const int* __restrict__ row_start,
                          const float* __restrict__ ea_s, const float* __restrict__ eW,
                          const float* __restrict__ eb, float* __restrict__ zin)
{
    int node = blockIdx.x * 4 + (threadIdx.x >> 6);
    if (node >= NN) return;
    int lane = threadIdx.x & 63;
    int c2 = lane * 2;
    float w0[EDGE_F], w1[EDGE_F];
    {
        const float* p = eW + c2 * EDGE_F;
#pragma unroll
        for (int f = 0; f < EDGE_F; ++f) { w0[f] = p[f]; w1[f] = p[EDGE_F + f]; }
    }
    float bx = eb[c2], by = eb[c2 + 1];
    float accx = 0.f, accy = 0.f;
    int beg = __builtin_amdgcn_readfirstlane(row_start[node]);
    int end = __builtin_amdgcn_readfirstlane(row_start[node + 1]);
    int j = beg;
    for (; j + 4 <= end; j += 4) {
        int s0 = srcs[j], s1 = srcs[j + 1], s2 = srcs[j + 2], s3 = srcs[j + 3];
        uint hv0 = hb[(size_t)s0 * 64 + lane];
        uint hv1 = hb[(size_t)s1 * 64 + lane];
        uint hv2 = hb[(size_t)s2 * 64 + lane];
        uint hv3 = hb[(size_t)s3 * 64 + lane];
        const float2* e0 = (const float2*)(ea_s + (size_t)j * EDGE_F);
        const float2* e1 = e0 + 7;
        const float2* e2 = e0 + 14;
        const float2* e3 = e0 + 21;
        EMSG(hv0, e0); EMSG(hv1, e1); EMSG(hv2, e2); EMSG(hv3, e3);
    }
    for (; j < end; ++j) {
        uint hv0 = hb[(size_t)srcs[j] * 64 + lane];
        const float2* e0 = (const float2*)(ea_s + (size_t)j * EDGE_F);
        EMSG(hv0, e0);
    }
    float2 hn = *(const float2*)&h[(size_t)node * HD + c2];
    *(float2*)&zin[(size_t)node * HD + c2] = make_float2(hn.x + accx, hn.y + accy);
}

// --------- fused layer: h = relu(relu(BN(zin@W1^T+b1))@W2^T+b2) + h --------
__global__ __launch_bounds__(256)
void fused_layer_kernel(const float* __restrict__ zin,
                        const ushort* __restrict__ w1b, const float* __restrict__ b1,
                        const float* __restrict__ gamma, const float* __restrict__ beta,
                        const float* __restrict__ mean, const float* __restrict__ var,
                        const ushort* __restrict__ w2b, const float* __restrict__ b2,
                        float* __restrict__ h, ushort* __restrict__ hb, int n)
{
    __shared__ uint Ahi[64 * 64];  // bf16[64][128], XOR-swizzled; reused for z
    __shared__ uint Alo[64 * 64];
    const int t = threadIdx.x;
    const int nb = blockIdx.x * 64;

    {
        int row = t >> 2;
        int kq = (t & 3) * 32;
        int gn = nb + row;
        uint hiw[16], low[16];
        if (gn < n) {
            const float4* src = (const float4*)(zin + (size_t)gn * HD + kq);
#pragma unroll
            for (int i = 0; i < 8; ++i) {
                float4 v = src[i];
                uint h0 = bfround(v.x), h1 = bfround(v.y), h2 = bfround(v.z), h3 = bfround(v.w);
                float r0 = v.x - __uint_as_float(h0 << 16);
                float r1 = v.y - __uint_as_float(h1 << 16);
                float r2 = v.z - __uint_as_float(h2 << 16);
                float r3 = v.w - __uint_as_float(h3 << 16);
                hiw[2 * i]     = h0 | (h1 << 16);
                hiw[2 * i + 1] = h2 | (h3 << 16);
                low[2 * i]     = bfround(r0) | (bfround(r1) << 16);
                low[2 * i + 1] = bfround(r2) | (bfround(r3) << 16);
            }
        } else {
#pragma unroll
            for (int i = 0; i < 16; ++i) { hiw[i] = 0; low[i] = 0; }
        }
        uint rowbase = row * 256;
#pragma unroll
        for (int i = 0; i < 4; ++i) {
            uint byte = (rowbase + (kq + 8 * i) * 2) ^ ((row & 7) << 4);
            *(uint4*)((char*)Ahi + byte) = make_uint4(hiw[4 * i], hiw[4 * i + 1], hiw[4 * i + 2], hiw[4 * i + 3]);
            *(uint4*)((char*)Alo + byte) = make_uint4(low[4 * i], low[4 * i + 1], low[4 * i + 2], low[4 * i + 3]);
        }
    }

    const int w  = t >> 6, l = t & 63;
    const int lc = l & 15, lk = l >> 4;
    bf16x8 wf1[2][4], wf2[2][4];
#pragma unroll
    for (int ct = 0; ct < 2; ++ct)
#pragma unroll
        for (int ks = 0; ks < 4; ++ks) {
            size_t off = (size_t)(w * 32 + ct * 16 + lc) * HD + ks * 32 + lk * 8;
            wf1[ct][ks] = *(const bf16x8*)(w1b + off);
            wf2[ct][ks] = *(const bf16x8*)(w2b + off);
        }

    __syncthreads();

    f32x4 acc[4][2];
#pragma unroll
    for (int rt = 0; rt < 4; ++rt)
#pragma unroll
        for (int ct = 0; ct < 2; ++ct) acc[rt][ct] = (f32x4){0.f, 0.f, 0.f, 0.f};

#pragma unroll
    for (int ks = 0; ks < 4; ++ks) {
#pragma unroll
        for (int rt = 0; rt < 4; ++rt) {
            int row = rt * 16 + lc;
            uint byte = ((uint)(row * 256 + (ks * 32 + lk * 8) * 2)) ^ ((row & 7) << 4);
            bf16x8 ah = *(const bf16x8*)((char*)Ahi + byte);
            bf16x8 al = *(const bf16x8*)((char*)Alo + byte);
            acc[rt][0] = __builtin_amdgcn_mfma_f32_16x16x32_bf16(ah, wf1[0][ks], acc[rt][0], 0, 0, 0);
            acc[rt][0] = __builtin_amdgcn_mfma_f32_16x16x32_bf16(al, wf1[0][ks], acc[rt][0], 0, 0, 0);
            acc[rt][1] = __builtin_amdgcn_mfma_f32_16x16x32_bf16(ah, wf1[1][ks], acc[rt][1], 0, 0, 0);
            acc[rt][1] = __builtin_amdgcn_mfma_f32_16x16x32_bf16(al, wf1[1][ks], acc[rt][1], 0, 0, 0);
        }
    }

    __syncthreads();

#pragma unroll
    for (int ct = 0; ct < 2; ++ct) {
        int col = w * 32 + ct * 16 + lc;
        float bi = b1[col];
        float scv = gamma[col] * rsqrtf(var[col] + BN_EPS);
        float shv = beta[col] - mean[col] * scv;
#pragma unroll
        for (int rt = 0; rt < 4; ++rt) {
#pragma unroll
            for (int r = 0; r < 4; ++r) {
                int rowl = rt * 16 + lk * 4 + r;
                float v = (acc[rt][ct][r] + bi) * scv + shv;
                v = fmaxf(v, 0.f);
                uint byte = ((uint)(rowl * 256 + col * 2)) ^ ((rowl & 7) << 4);
                *(ushort*)((char*)Ahi + byte) = (ushort)bfround(v);
            }
        }
    }

    __syncthreads();

    f32x4 acc2[4][2];
#pragma unroll
    for (int rt = 0; rt < 4; ++rt)
#pragma unroll
        for (int ct = 0; ct < 2; ++ct) acc2[rt][ct] = (f32x4){0.f, 0.f, 0.f, 0.f};

#pragma unroll
    for (int ks = 0; ks < 4; ++ks) {
#pragma unroll
        for (int rt = 0; rt < 4; ++rt) {
            int row = rt * 16 + lc;
            uint byte = ((uint)(row * 256 + (ks * 32 + lk * 8) * 2)) ^ ((row & 7) << 4);
            bf16x8 az = *(const bf16x8*)((char*)Ahi + byte);
            acc2[rt][0] = __builtin_amdgcn_mfma_f32_16x16x32_bf16(az, wf2[0][ks], acc2[rt][0], 0, 0, 0);
            acc2[rt][1] = __builtin_amdgcn_mfma_f32_16x16x32_bf16(az, wf2[1][ks], acc2[rt][1], 0, 0, 0);
        }
    }

#pragma unroll
    for (int ct = 0; ct < 2; ++ct) {
        int col = w * 32 + ct * 16 + lc;
        float bi = b2[col];
#pragma unroll
        for (int rt = 0; rt < 4; ++rt) {
#pragma unroll
            for (int r = 0; r < 4; ++r) {
                int row = nb + rt * 16 + lk * 4 + r;
                if (row < n) {
                    float v = fmaxf(acc2[rt][ct][r] + bi, 0.f) + h[(size_t)row * HD + col];
                    h[(size_t)row * HD + col] = v;
                    hb[(size_t)row * HD + col] = (ushort)bfround(v);
                }
            }
        }
    }
}

// -------- pooling: sorted batch_idx -> chunked local sums, rare atomics ----
__global__ __launch_bounds__(128)
void pool_kernel(const float* __restrict__ h, const int* __restrict__ batch,
                 float* __restrict__ pooled, int* __restrict__ counts, int n, int chunk)
{
    int c = threadIdx.x;
    int n_start = blockIdx.x * chunk;
    if (n_start >= n) return;
    int n_end = min(n_start + chunk, n);
    float local = 0.f;
    int cnt = 0;
    int g_cur = batch[n_start];
    for (int nd = n_start; nd < n_end; ++nd) {
        int g = batch[nd];
        if (g != g_cur) {
            atomicAdd(&pooled[g_cur * HD + c], local);
            if (c == 0) atomicAdd(&counts[g_cur], cnt);
            local = 0.f; cnt = 0; g_cur = g;
        }
        local += h[(size_t)nd * HD + c];
        cnt++;
    }
    atomicAdd(&pooled[g_cur * HD + c], local);
    if (c == 0) atomicAdd(&counts[g_cur], cnt);
}

__global__ __launch_bounds__(128)
void final_kernel(const float* __restrict__ pooled, const int* __restrict__ counts,
                  const float* __restrict__ projT, const float* __restrict__ pb,
                  float* __restrict__ out)
{
    __shared__ float p_lds[HD];
    int g = blockIdx.x, p = threadIdx.x;
    float inv = 1.f / fmaxf((float)counts[g], 1.f);
    p_lds[p] = pooled[g * HD + p];
    __syncthreads();
    float acc = 0.f;
#pragma unroll 4
    for (int c = 0; c < HD; ++c) acc += p_lds[c] * projT[c * HD + p];
    out[g * HD + p] = acc * inv + pb[p];
}

extern "C" void kernel_launch(void* const* d_in, const int* in_sizes, int n_in,
                              void* d_out, int out_size, void* d_ws, size_t ws_size,
                              hipStream_t stream)
{
    const float* x        = (const float*)d_in[0];
    const int*   edge_idx = (const int*)d_in[1];
    const float* edge_attr= (const float*)d_in[2];
    const int*   batch    = (const int*)d_in[3];
    const float* node_W   = (const float*)d_in[4];
    const float* node_b   = (const float*)d_in[5];
    const float* edge_W   = (const float*)d_in[6];
    const float* edge_b   = (const float*)d_in[7];
    const float* lin1_b   = (const float*)d_in[9];
    const float* bn_gamma = (const float*)d_in[10];
    const float* bn_beta  = (const float*)d_in[11];
    const float* bn_mean  = (const float*)d_in[12];
    const float* bn_var   = (const float*)d_in[13];
    const float* lin2_b   = (const float*)d_in[15];
    const float* proj_b   = (const float*)d_in[17];

    char* ws = (char*)d_ws;
    float*  h        = (float*) (ws);                  // 25.6 MB
    float*  zin      = (float*) (ws + 25600000);       // 25.6 MB
    uint*   hb       = (uint*)  (ws + 51200000);       // 12.8 MB (packed bf16, 2ch/uint)
    int*    srcs     = (int*)   (ws + 64000000);       // 3.2 MB
    int*    eid      = (int*)   (ws + 67200000);       // 3.2 MB
    ushort* wb       = (ushort*)(ws + 70400000);       // 196,608
    float*  projT    = (float*) (ws + 70600000);       // 65,536
    float*  pooled   = (float*) (ws + 70700000);       // 32,768
    int*    counts   = (int*)   (ws + 70732768);       // 256 (contiguous after pooled)
    int*    deg      = (int*)   (ws + 70740000);       // 200,000
    int*    incl     = (int*)   (ws + 70940000);       // 200,000
    int*    bsum     = (int*)   (ws + 71140000);       // 1,024
    int*    bscan    = (int*)   (ws + 71142048);       // 1,024
    int*    row_start= (int*)   (ws + 71144096);       // 200,064
    int*    cursor   = (int*)   (ws + 71344160);       // 200,000
    // path-specific region at 72 MB:
    uchar*  emb      = (uchar*) (ws + 72000000);       // 102.4 MB fp8 (emb path)
    float*  ea_s     = (float*) (ws + 72000000);       // 44.8 MB (fallback path)
    const bool use_emb = (ws_size >= (size_t)174400000);

    const int NB = (NN + 255) / 256;  // 196

    // --- CSR build (edge_index constant across layers) ---
    hipMemsetAsync(deg, 0, NN * sizeof(int), stream);
    hist_kernel<<<(NE + 255) / 256, 256, 0, stream>>>(edge_idx, deg);
    scan1_kernel<<<NB, 256, 0, stream>>>(deg, incl, bsum);
    scan2_kernel<<<1, 256, 0, stream>>>(bsum, bscan, NB);
    scan3_kernel<<<NB, 256, 0, stream>>>(deg, incl, bscan, row_start, cursor);
    scatter_kernel<<<(NE + 255) / 256, 256, 0, stream>>>(edge_idx, cursor, srcs, eid);

    if (use_emb) {
        embed_edges_kernel<<<NE / EB, 256, 0, stream>>>(
            edge_attr, eid, edge_W, edge_b, emb);
    } else {
        permute_ea_kernel<<<(NE * 7 + 255) / 256, 256, 0, stream>>>(edge_attr, eid, ea_s);
    }

    init_kernel<<<448 + (NN * 64 + 255) / 256, 256, 0, stream>>>(
        x, node_W, node_b, (const float*)d_in[8], (const float*)d_in[14],
        (const float*)d_in[16], h, hb, wb, projT);

    for (int i = 0; i < NL; ++i) {
        if (use_emb) {
            agg_emb_kernel<<<(NN + 3) / 4, 256, 0, stream>>>(
                h, hb, srcs, row_start, emb, zin);
        } else {
            agg_recompute_kernel<<<(NN + 3) / 4, 256, 0, stream>>>(
                h, hb, srcs, row_start, ea_s, edge_W, edge_b, zin);
        }
        fused_layer_kernel<<<(NN + 63) / 64, 256, 0, stream>>>(
            zin, wb + (size_t)i * HD * HD, lin1_b + i * HD,
            bn_gamma + i * HD, bn_beta + i * HD, bn_mean + i * HD, bn_var + i * HD,
            wb + (size_t)(3 + i) * HD * HD, lin2_b + i * HD,
            h, (ushort*)hb, NN);
    }

    hipMemsetAsync(pooled, 0, NG * HD * sizeof(float) + NG * sizeof(int) + 4000, stream);
    pool_kernel<<<(NN + 31) / 32, 128, 0, stream>>>(h, batch, pooled, counts, NN, 32);
    final_kernel<<<NG, HD, 0, stream>>>(pooled, counts, projT, proj_b, (float*)d_out);
}

// Round 10
// 471.099 us; speedup vs baseline: 1.3015x; 1.0029x over previous
//
#include <hip/hip_runtime.h>

typedef unsigned int uint;
typedef unsigned short ushort;
typedef unsigned char uchar;
typedef __attribute__((ext_vector_type(8))) short bf16x8;
typedef __attribute__((ext_vector_type(4))) float f32x4;

#define NN 50000
#define NE 800000
#define NG 64
#define NODE_F 11
#define EDGE_F 14
#define HD 128
#define NL 3
#define BN_EPS 1e-5f

#if defined(__has_builtin)
#if __has_builtin(__builtin_amdgcn_cvt_f32_fp8) && __has_builtin(__builtin_amdgcn_cvt_pk_fp8_f32)
#define HW_FP8 1
#endif
#endif

__device__ __forceinline__ uint bfround(float v) {
    uint b = __float_as_uint(v);
    return (b + 0x7fffu + ((b >> 16) & 1u)) >> 16;
}

#ifndef HW_FP8
__device__ __forceinline__ uint f8enc(float v) {
    float a = fabsf(v);
    uint s = (__float_as_uint(v) >> 31) << 7;
    if (!(a > 0.f)) return s;
    if (a >= 448.f) return s | 0x7e;
    uint ab = __float_as_uint(a);
    int e = (int)(ab >> 23) - 127;
    uint m = ab & 0x7fffffu;
    if (e < -6) {
        if (e < -10) return s;
        uint full = 0x800000u | m;
        int shift = 14 - e;
        uint q = full >> shift;
        uint rem = full & ((1u << shift) - 1u);
        uint half = 1u << (shift - 1);
        if (rem > half || (rem == half && (q & 1))) q++;
        return s | q;
    }
    uint m3 = m >> 20;
    uint rem = m & 0xfffffu;
    if (rem > 0x80000u || (rem == 0x80000u && (m3 & 1))) {
        m3++;
        if (m3 == 8) { m3 = 0; e++; }
    }
    if (e > 8 || (e == 8 && m3 > 6)) return s | 0x7e;
    return s | ((uint)(e + 7) << 3) | m3;
}
__device__ __forceinline__ float f8dec(uint x) {
    uint e = (x >> 3) & 15u, m = x & 7u;
    float v = (e == 0) ? ldexpf((float)m, -9) : ldexpf((float)(8u + m), (int)e - 10);
    return (x & 0x80u) ? -v : v;
}
#endif

// ------- init: prep weights (blocks 0..447) + node embedding (rest) --------
__global__ __launch_bounds__(256)
void init_kernel(const float* __restrict__ x, const float* __restrict__ nW,
                 const float* __restrict__ nb_, const float* __restrict__ lin1,
                 const float* __restrict__ lin2, const float* __restrict__ proj,
                 float* __restrict__ h, uint* __restrict__ hb,
                 ushort* __restrict__ wb, float* __restrict__ projT)
{
    int bid = blockIdx.x;
    if (bid < 448) {
        int idx = bid * 256 + threadIdx.x;
        if (idx >= 7 * HD * HD) return;
        if (idx < 6 * HD * HD) {
            int m = idx >> 14, e = idx & (HD * HD - 1);
            const float* src = (m < 3) ? (lin1 + m * HD * HD) : (lin2 + (m - 3) * HD * HD);
            wb[idx] = (ushort)bfround(src[e]);
        } else {
            int e = idx - 6 * HD * HD;
            int r = e >> 7, c = e & 127;
            projT[c * HD + r] = proj[r * HD + c];
        }
    } else {
        int idx = (bid - 448) * 256 + threadIdx.x;
        if (idx >= NN * 64) return;
        int node = idx >> 6, cp = idx & 63;
        int c2 = cp * 2;
        const float* xr = x + node * NODE_F;
        const float* w0 = nW + c2 * NODE_F;
        const float* w1 = w0 + NODE_F;
        float a0 = nb_[c2], a1 = nb_[c2 + 1];
#pragma unroll
        for (int f = 0; f < NODE_F; ++f) { float xv = xr[f]; a0 += xv * w0[f]; a1 += xv * w1[f]; }
        *(float2*)&h[(size_t)node * HD + c2] = make_float2(a0, a1);
        hb[idx] = bfround(a0) | (bfround(a1) << 16);
    }
}

// ----------------------------- CSR construction ----------------------------
__global__ __launch_bounds__(256)
void hist_kernel(const int* __restrict__ ei, int* __restrict__ deg)
{
    int e = blockIdx.x * 256 + threadIdx.x;
    if (e < NE) atomicAdd(&deg[ei[NE + e]], 1);
}

__global__ __launch_bounds__(256)
void scan1_kernel(const int* __restrict__ deg, int* __restrict__ incl, int* __restrict__ bsum)
{
    int i = blockIdx.x * 256 + threadIdx.x;
    int v = (i < NN) ? deg[i] : 0;
    int lane = threadIdx.x & 63;
#pragma unroll
    for (int off = 1; off < 64; off <<= 1) {
        int u = __shfl_up(v, off);
        if (lane >= off) v += u;
    }
    __shared__ int wsum[4];
    if (lane == 63) wsum[threadIdx.x >> 6] = v;
    __syncthreads();
    int wid = threadIdx.x >> 6;
    int add = 0;
#pragma unroll
    for (int w = 0; w < 3; ++w) if (w < wid) add += wsum[w];
    v += add;
    if (i < NN) incl[i] = v;
    if (threadIdx.x == 255) bsum[blockIdx.x] = v;
}

__global__ __launch_bounds__(256)
void scan2_kernel(const int* __restrict__ bsum, int* __restrict__ bscan, int nb)
{
    int i = threadIdx.x;
    int v = (i < nb) ? bsum[i] : 0;
    int lane = i & 63;
#pragma unroll
    for (int off = 1; off < 64; off <<= 1) {
        int u = __shfl_up(v, off);
        if (lane >= off) v += u;
    }
    __shared__ int wsum[4];
    if (lane == 63) wsum[i >> 6] = v;
    __syncthreads();
    int wid = i >> 6;
    int add = 0;
#pragma unroll
    for (int w = 0; w < 3; ++w) if (w < wid) add += wsum[w];
    v += add;
    bscan[i] = v;
}

__global__ __launch_bounds__(256)
void scan3_kernel(const int* __restrict__ deg, const int* __restrict__ incl,
                  const int* __restrict__ bscan, int* __restrict__ row_start,
                  int* __restrict__ cursor)
{
    int i = blockIdx.x * 256 + threadIdx.x;
    if (i >= NN) return;
    int b = blockIdx.x;
    int base = (b > 0) ? bscan[b - 1] : 0;
    int rs = base + incl[i] - deg[i];
    row_start[i] = rs;
    cursor[i] = rs;
    if (i == 0) row_start[NN] = NE;
}

__global__ __launch_bounds__(256)
void scatter_kernel(const int* __restrict__ ei, int* __restrict__ cursor,
                    int* __restrict__ srcs, int* __restrict__ eid)
{
    int e = blockIdx.x * 256 + threadIdx.x;
    if (e >= NE) return;
    int s = ei[e], d = ei[NE + e];
    int pos = atomicAdd(&cursor[d], 1);
    srcs[pos] = s;
    eid[pos] = e;
}

// -- one-time: emb[j] = fp8(edge_attr[eid[j]] @ eW^T + eb), dst-sorted order --
// Block = 128 edges. Gather tile padded to 16 floats/edge: idx -> (idx>>3, idx&7)
// (shift/mask, no div). Compute: weights in 7 float4 regs/lane, LDS broadcasts.
#define EB 128
__global__ __launch_bounds__(256)
void embed_edges_kernel(const float* __restrict__ ea, const int* __restrict__ eid,
                        const float* __restrict__ eW, const float* __restrict__ eb,
                        uchar* __restrict__ emb)
{
    __shared__ int eid_lds[EB];
    __shared__ float tile[EB][16];   // padded to 16 -> shift/mask indexing
    const int t = threadIdx.x;
    const int j0 = blockIdx.x * EB;

    if (t < EB) eid_lds[t] = eid[j0 + t];

    int lane = t & 63;
    const float4* wp = (const float4*)(eW + lane * 28);
    float4 q0 = wp[0], q1 = wp[1], q2 = wp[2], q3 = wp[3], q4 = wp[4], q5 = wp[5], q6 = wp[6];
    float2 ebv = *(const float2*)&eb[lane * 2];

    __syncthreads();

    // 4 rounds x 256 threads = 1024 slots; slot -> edge idx>>3, feature-pair idx&7
#pragma unroll
    for (int rep = 0; rep < 4; ++rep) {
        int idx = rep * 256 + t;
        int el = idx >> 3, f2 = idx & 7;
        if (f2 < 7) {
            float2 v = *(const float2*)(ea + (size_t)eid_lds[el] * EDGE_F + 2 * f2);
            *(float2*)&tile[el][2 * f2] = v;
        }
    }
    __syncthreads();

    const int w = t >> 6;
    const int c2 = lane * 2;
#pragma unroll 4
    for (int el = w * 32; el < w * 32 + 32; ++el) {
        float2 a0 = *(const float2*)&tile[el][0];
        float2 a1 = *(const float2*)&tile[el][2];
        float2 a2 = *(const float2*)&tile[el][4];
        float2 a3 = *(const float2*)&tile[el][6];
        float2 a4 = *(const float2*)&tile[el][8];
        float2 a5 = *(const float2*)&tile[el][10];
        float2 a6 = *(const float2*)&tile[el][12];
        float ax = ebv.x, ay = ebv.y;
        ax += a0.x * q0.x + a0.y * q0.y;
        ax += a1.x * q0.z + a1.y * q0.w;
        ax += a2.x * q1.x + a2.y * q1.y;
        ax += a3.x * q1.z + a3.y * q1.w;
        ax += a4.x * q2.x + a4.y * q2.y;
        ax += a5.x * q2.z + a5.y * q2.w;
        ax += a6.x * q3.x + a6.y * q3.y;
        ay += a0.x * q3.z + a0.y * q3.w;
        ay += a1.x * q4.x + a1.y * q4.y;
        ay += a2.x * q4.z + a2.y * q4.w;
        ay += a3.x * q5.x + a3.y * q5.y;
        ay += a4.x * q5.z + a4.y * q5.w;
        ay += a5.x * q6.x + a5.y * q6.y;
        ay += a6.x * q6.z + a6.y * q6.w;
        ushort st;
#ifdef HW_FP8
        uint pk = (uint)__builtin_amdgcn_cvt_pk_fp8_f32(ax, ay, 0, false);
        st = (ushort)(pk & 0xffffu);
#else
        st = (ushort)(f8enc(ax) | (f8enc(ay) << 8));
#endif
        *(ushort*)(emb + (size_t)(j0 + el) * HD + c2) = st;
    }
}

// ------ agg (fp8 emb): zin[n] = h[n] + sum_j relu(hb[src_j] + emb[j]) ------
// 16-deep load batches (then 8/4/1) -> 2x MLP; strictly ascending j order.
#ifdef HW_FP8
#define DEC2(EV, EX, EY)                                                    \
    float EX = __builtin_amdgcn_cvt_f32_fp8((int)(EV), 0);                  \
    float EY = __builtin_amdgcn_cvt_f32_fp8((int)(EV), 1);
#else
#define DEC2(EV, EX, EY)                                                    \
    float EX = lut[(EV) & 0xff];                                            \
    float EY = lut[((EV) >> 8) & 0xff];
#endif

#define MSGF(HV, EX, EY)                                                    \
    {                                                                       \
        float hx = __uint_as_float((HV) << 16);                             \
        float hy = __uint_as_float((HV) & 0xffff0000u);                     \
        accx += fmaxf(hx + (EX), 0.f);                                      \
        accy += fmaxf(hy + (EY), 0.f);                                      \
    }

__global__ __launch_bounds__(256)
void agg_emb_kernel(const float* __restrict__ h, const uint* __restrict__ hb,
                    const int* __restrict__ srcs, const int* __restrict__ row_start,
                    const uchar* __restrict__ emb, float* __restrict__ zin)
{
#ifndef HW_FP8
    __shared__ float lut[256];
    lut[threadIdx.x & 255] = f8dec(threadIdx.x & 255);
    __syncthreads();
#endif
    int node = blockIdx.x * 4 + (threadIdx.x >> 6);
    if (node >= NN) return;
    int lane = threadIdx.x & 63;
    int c2 = lane * 2;
    float accx = 0.f, accy = 0.f;
    int beg = __builtin_amdgcn_readfirstlane(row_start[node]);
    int end = __builtin_amdgcn_readfirstlane(row_start[node + 1]);
    int j = beg;
    for (; j + 16 <= end; j += 16) {
        int s[16];
        uint hv[16], ev[16];
#pragma unroll
        for (int q = 0; q < 16; ++q) s[q] = srcs[j + q];
#pragma unroll
        for (int q = 0; q < 16; ++q) {
            hv[q] = hb[(size_t)s[q] * 64 + lane];
            ev[q] = *(const ushort*)(emb + (size_t)(j + q) * HD + c2);
        }
#pragma unroll
        for (int q = 0; q < 16; ++q) { DEC2(ev[q], ex, ey) MSGF(hv[q], ex, ey) }
    }
    for (; j + 8 <= end; j += 8) {
        int s[8];
        uint hv[8], ev[8];
#pragma unroll
        for (int q = 0; q < 8; ++q) s[q] = srcs[j + q];
#pragma unroll
        for (int q = 0; q < 8; ++q) {
            hv[q] = hb[(size_t)s[q] * 64 + lane];
            ev[q] = *(const ushort*)(emb + (size_t)(j + q) * HD + c2);
        }
#pragma unroll
        for (int q = 0; q < 8; ++q) { DEC2(ev[q], ex, ey) MSGF(hv[q], ex, ey) }
    }
    for (; j + 4 <= end; j += 4) {
        int s0 = srcs[j], s1 = srcs[j + 1], s2 = srcs[j + 2], s3 = srcs[j + 3];
        uint hv0 = hb[(size_t)s0 * 64 + lane];
        uint hv1 = hb[(size_t)s1 * 64 + lane];
        uint hv2 = hb[(size_t)s2 * 64 + lane];
        uint hv3 = hb[(size_t)s3 * 64 + lane];
        uint ev0 = *(const ushort*)(emb + (size_t)j * HD + c2);
        uint ev1 = *(const ushort*)(emb + (size_t)(j + 1) * HD + c2);
        uint ev2 = *(const ushort*)(emb + (size_t)(j + 2) * HD + c2);
        uint ev3 = *(const ushort*)(emb + (size_t)(j + 3) * HD + c2);
        { DEC2(ev0, ex, ey) MSGF(hv0, ex, ey) }
        { DEC2(ev1, ex, ey) MSGF(hv1, ex, ey) }
        { DEC2(ev2, ex, ey) MSGF(hv2, ex, ey) }
        { DEC2(ev3, ex, ey) MSGF(hv3, ex, ey) }
    }
    for (; j < end; ++j) {
        uint hv0 = hb[(size_t)srcs[j] * 64 + lane];
        uint ev0 = *(const ushort*)(emb + (size_t)j * HD + c2);
        { DEC2(ev0, ex, ey) MSGF(hv0, ex, ey) }
    }
    float2 hn = *(const float2*)&h[(size_t)node * HD + c2];
    *(float2*)&zin[(size_t)node * HD + c2] = make_float2(hn.x + accx, hn.y + accy);
}

// ------ agg (fallback, recompute): proven round-5 path, dst-sorted ea_s ----
#define EMSG(HV, EP)                                                       \
    {                                                                      \
        float ax = bx, ay = by;                                            \
        _Pragma("unroll")                                                  \
        for (int f2 = 0; f2 < 7; ++f2) {                                   \
            float2 av = (EP)[f2];                                          \
            ax += av.x * w0[2 * f2] + av.y * w0[2 * f2 + 1];               \
            ay += av.x * w1[2 * f2] + av.y * w1[2 * f2 + 1];               \
        }                                                                  \
        float hx = __uint_as_float((HV) << 16);                            \
        float hy = __uint_as_float((HV) & 0xffff0000u);                    \
        accx += fmaxf(hx + ax, 0.f);                                       \
        accy += fmaxf(hy + ay, 0.f);                                       \
    }

__global__ __launch_bounds__(256)
void permute_ea_kernel(const float* __restrict__ ea, const int* __restrict__ eid,
                       float* __restrict__ ea_s)
{
    int idx = blockIdx.x * 256 + threadIdx.x;
    if (idx >= NE * 7) return;
    int e = idx / 7, f2 = idx % 7;
    float2 v = *(const float2*)(ea + (size_t)eid[e] * EDGE_F + f2 * 2);
    *(float2*)(ea_s + (size_t)e * EDGE_F + f2 * 2) = v;
}

__global__ __launch_bounds__(256)
void agg_recompute_kernel(const float* __restrict__ h, const uint* __restrict__ hb,
                          const int* __restrict__ srcs, const int* __restrict__ row_start,
                          const float* __restrict__ ea_s, const float* __restrict__ eW,
                          const float* __restrict__ eb, float* __restrict__ zin)
{
    int node = blockIdx.x * 4 + (threadIdx.x >> 6);
    if (node >= NN) return;
    int lane = threadIdx.x & 63;
    int c2 = lane * 2;
    float w0[EDGE_F], w1[EDGE_F];
    {
        const float* p = eW + c2 * EDGE_F;
#pragma unroll
        for (int f = 0; f < EDGE_F; ++f) { w0[f] = p[f]; w1[f] = p[EDGE_F + f]; }
    }
    float bx = eb[c2], by = eb[c2 + 1];
    float accx = 0.f, accy = 0.f;
    int beg = __builtin_amdgcn_readfirstlane(row_start[node]);
    int end = __builtin_amdgcn_readfirstlane(row_start[node + 1]);
    int j = beg;
    for (; j + 4 <= end; j += 4) {
        int s0 = srcs[j], s1 = srcs[j + 1], s2 = srcs[j + 2], s3 = srcs[j + 3];
        uint hv0 = hb[(size_t)s0 * 64 + lane];
        uint hv1 = hb[(size_t)s1 * 64 + lane];
        uint hv2 = hb[(size_t)s2 * 64 + lane];
        uint hv3 = hb[(size_t)s3 * 64 + lane];
        const float2* e0 = (const float2*)(ea_s + (size_t)j * EDGE_F);
        const float2* e1 = e0 + 7;
        const float2* e2 = e0 + 14;
        const float2* e3 = e0 + 21;
        EMSG(hv0, e0); EMSG(hv1, e1); EMSG(hv2, e2); EMSG(hv3, e3);
    }
    for (; j < end; ++j) {
        uint hv0 = hb[(size_t)srcs[j] * 64 + lane];
        const float2* e0 = (const float2*)(ea_s + (size_t)j * EDGE_F);
        EMSG(hv0, e0);
    }
    float2 hn = *(const float2*)&h[(size_t)node * HD + c2];
    *(float2*)&zin[(size_t)node * HD + c2] = make_float2(hn.x + accx, hn.y + accy);
}

// --------- fused layer: h = relu(relu(BN(zin@W1^T+b1))@W2^T+b2) + h --------
__global__ __launch_bounds__(256)
void fused_layer_kernel(const float* __restrict__ zin,
                        const ushort* __restrict__ w1b, const float* __restrict__ b1,
                        const float* __restrict__ gamma, const float* __restrict__ beta,
                        const float* __restrict__ mean, const float* __restrict__ var,
                        const ushort* __restrict__ w2b, const float* __restrict__ b2,
                        float* __restrict__ h, ushort* __restrict__ hb, int n)
{
    __shared__ uint Ahi[64 * 64];  // bf16[64][128], XOR-swizzled; reused for z
    __shared__ uint Alo[64 * 64];
    const int t = threadIdx.x;
    const int nb = blockIdx.x * 64;

    {
        int row = t >> 2;
        int kq = (t & 3) * 32;
        int gn = nb + row;
        uint hiw[16], low[16];
        if (gn < n) {
            const float4* src = (const float4*)(zin + (size_t)gn * HD + kq);
#pragma unroll
            for (int i = 0; i < 8; ++i) {
                float4 v = src[i];
                uint h0 = bfround(v.x), h1 = bfround(v.y), h2 = bfround(v.z), h3 = bfround(v.w);
                float r0 = v.x - __uint_as_float(h0 << 16);
                float r1 = v.y - __uint_as_float(h1 << 16);
                float r2 = v.z - __uint_as_float(h2 << 16);
                float r3 = v.w - __uint_as_float(h3 << 16);
                hiw[2 * i]     = h0 | (h1 << 16);
                hiw[2 * i + 1] = h2 | (h3 << 16);
                low[2 * i]     = bfround(r0) | (bfround(r1) << 16);
                low[2 * i + 1] = bfround(r2) | (bfround(r3) << 16);
            }
        } else {
#pragma unroll
            for (int i = 0; i < 16; ++i) { hiw[i] = 0; low[i] = 0; }
        }
        uint rowbase = row * 256;
#pragma unroll
        for (int i = 0; i < 4; ++i) {
            uint byte = (rowbase + (kq + 8 * i) * 2) ^ ((row & 7) << 4);
            *(uint4*)((char*)Ahi + byte) = make_uint4(hiw[4 * i], hiw[4 * i + 1], hiw[4 * i + 2], hiw[4 * i + 3]);
            *(uint4*)((char*)Alo + byte) = make_uint4(low[4 * i], low[4 * i + 1], low[4 * i + 2], low[4 * i + 3]);
        }
    }

    const int w  = t >> 6, l = t & 63;
    const int lc = l & 15, lk = l >> 4;
    bf16x8 wf1[2][4], wf2[2][4];
#pragma unroll
    for (int ct = 0; ct < 2; ++ct)
#pragma unroll
        for (int ks = 0; ks < 4; ++ks) {
            size_t off = (size_t)(w * 32 + ct * 16 + lc) * HD + ks * 32 + lk * 8;
            wf1[ct][ks] = *(const bf16x8*)(w1b + off);
            wf2[ct][ks] = *(const bf16x8*)(w2b + off);
        }

    __syncthreads();

    f32x4 acc[4][2];
#pragma unroll
    for (int rt = 0; rt < 4; ++rt)
#pragma unroll
        for (int ct = 0; ct < 2; ++ct) acc[rt][ct] = (f32x4){0.f, 0.f, 0.f, 0.f};

#pragma unroll
    for (int ks = 0; ks < 4; ++ks) {
#pragma unroll
        for (int rt = 0; rt < 4; ++rt) {
            int row = rt * 16 + lc;
            uint byte = ((uint)(row * 256 + (ks * 32 + lk * 8) * 2)) ^ ((row & 7) << 4);
            bf16x8 ah = *(const bf16x8*)((char*)Ahi + byte);
            bf16x8 al = *(const bf16x8*)((char*)Alo + byte);
            acc[rt][0] = __builtin_amdgcn_mfma_f32_16x16x32_bf16(ah, wf1[0][ks], acc[rt][0], 0, 0, 0);
            acc[rt][0] = __builtin_amdgcn_mfma_f32_16x16x32_bf16(al, wf1[0][ks], acc[rt][0], 0, 0, 0);
            acc[rt][1] = __builtin_amdgcn_mfma_f32_16x16x32_bf16(ah, wf1[1][ks], acc[rt][1], 0, 0, 0);
            acc[rt][1] = __builtin_amdgcn_mfma_f32_16x16x32_bf16(al, wf1[1][ks], acc[rt][1], 0, 0, 0);
        }
    }

    __syncthreads();

#pragma unroll
    for (int ct = 0; ct < 2; ++ct) {
        int col = w * 32 + ct * 16 + lc;
        float bi = b1[col];
        float scv = gamma[col] * rsqrtf(var[col] + BN_EPS);
        float shv = beta[col] - mean[col] * scv;
#pragma unroll
        for (int rt = 0; rt < 4; ++rt) {
#pragma unroll
            for (int r = 0; r < 4; ++r) {
                int rowl = rt * 16 + lk * 4 + r;
                float v = (acc[rt][ct][r] + bi) * scv + shv;
                v = fmaxf(v, 0.f);
                uint byte = ((uint)(rowl * 256 + col * 2)) ^ ((rowl & 7) << 4);
                *(ushort*)((char*)Ahi + byte) = (ushort)bfround(v);
            }
        }
    }

    __syncthreads();

    f32x4 acc2[4][2];
#pragma unroll
    for (int rt = 0; rt < 4; ++rt)
#pragma unroll
        for (int ct = 0; ct < 2; ++ct) acc2[rt][ct] = (f32x4){0.f, 0.f, 0.f, 0.f};

#pragma unroll
    for (int ks = 0; ks < 4; ++ks) {
#pragma unroll
        for (int rt = 0; rt < 4; ++rt) {
            int row = rt * 16 + lc;
            uint byte = ((uint)(row * 256 + (ks * 32 + lk * 8) * 2)) ^ ((row & 7) << 4);
            bf16x8 az = *(const bf16x8*)((char*)Ahi + byte);
            acc2[rt][0] = __builtin_amdgcn_mfma_f32_16x16x32_bf16(az, wf2[0][ks], acc2[rt][0], 0, 0, 0);
            acc2[rt][1] = __builtin_amdgcn_mfma_f32_16x16x32_bf16(az, wf2[1][ks], acc2[rt][1], 0, 0, 0);
        }
    }

#pragma unroll
    for (int ct = 0; ct < 2; ++ct) {
        int col = w * 32 + ct * 16 + lc;
        float bi = b2[col];
#pragma unroll
        for (int rt = 0; rt < 4; ++rt) {
#pragma unroll
            for (int r = 0; r < 4; ++r) {
                int row = nb + rt * 16 + lk * 4 + r;
                if (row < n) {
                    float v = fmaxf(acc2[rt][ct][r] + bi, 0.f) + h[(size_t)row * HD + col];
                    h[(size_t)row * HD + col] = v;
                    hb[(size_t)row * HD + col] = (ushort)bfround(v);
                }
            }
        }
    }
}

// -------- pooling: sorted batch_idx -> chunked local sums, rare atomics ----
__global__ __launch_bounds__(128)
void pool_kernel(const float* __restrict__ h, const int* __restrict__ batch,
                 float* __restrict__ pooled, int* __restrict__ counts, int n, int chunk)
{
    int c = threadIdx.x;
    int n_start = blockIdx.x * chunk;
    if (n_start >= n) return;
    int n_end = min(n_start + chunk, n);
    float local = 0.f;
    int cnt = 0;
    int g_cur = batch[n_start];
    for (int nd = n_start; nd < n_end; ++nd) {
        int g = batch[nd];
        if (g != g_cur) {
            atomicAdd(&pooled[g_cur * HD + c], local);
            if (c == 0) atomicAdd(&counts[g_cur], cnt);
            local = 0.f; cnt = 0; g_cur = g;
        }
        local += h[(size_t)nd * HD + c];
        cnt++;
    }
    atomicAdd(&pooled[g_cur * HD + c], local);
    if (c == 0) atomicAdd(&counts[g_cur], cnt);
}

__global__ __launch_bounds__(128)
void final_kernel(const float* __restrict__ pooled, const int* __restrict__ counts,
                  const float* __restrict__ projT, const float* __restrict__ pb,
                  float* __restrict__ out)
{
    __shared__ float p_lds[HD];
    int g = blockIdx.x, p = threadIdx.x;
    float inv = 1.f / fmaxf((float)counts[g], 1.f);
    p_lds[p] = pooled[g * HD + p];
    __syncthreads();
    float acc = 0.f;
#pragma unroll 4
    for (int c = 0; c < HD; ++c) acc += p_lds[c] * projT[c * HD + p];
    out[g * HD + p] = acc * inv + pb[p];
}

extern "C" void kernel_launch(void* const* d_in, const int* in_sizes, int n_in,
                              void* d_out, int out_size, void* d_ws, size_t ws_size,
                              hipStream_t stream)
{
    const float* x        = (const float*)d_in[0];
    const int*   edge_idx = (const int*)d_in[1];
    const float* edge_attr= (const float*)d_in[2];
    const int*   batch    = (const int*)d_in[3];
    const float* node_W   = (const float*)d_in[4];
    const float* node_b   = (const float*)d_in[5];
    const float* edge_W   = (const float*)d_in[6];
    const float* edge_b   = (const float*)d_in[7];
    const float* lin1_b   = (const float*)d_in[9];
    const float* bn_gamma = (const float*)d_in[10];
    const float* bn_beta  = (const float*)d_in[11];
    const float* bn_mean  = (const float*)d_in[12];
    const float* bn_var   = (const float*)d_in[13];
    const float* lin2_b   = (const float*)d_in[15];
    const float* proj_b   = (const float*)d_in[17];

    char* ws = (char*)d_ws;
    float*  h        = (float*) (ws);                  // 25.6 MB
    float*  zin      = (float*) (ws + 25600000);       // 25.6 MB
    uint*   hb       = (uint*)  (ws + 51200000);       // 12.8 MB (packed bf16, 2ch/uint)
    int*    srcs     = (int*)   (ws + 64000000);       // 3.2 MB
    int*    eid      = (int*)   (ws + 67200000);       // 3.2 MB
    ushort* wb       = (ushort*)(ws + 70400000);       // 196,608
    float*  projT    = (float*) (ws + 70600000);       // 65,536
    float*  pooled   = (float*) (ws + 70700000);       // 32,768
    int*    counts   = (int*)   (ws + 70732768);       // 256 (contiguous after pooled)
    int*    deg      = (int*)   (ws + 70740000);       // 200,000
    int*    incl     = (int*)   (ws + 70940000);       // 200,000
    int*    bsum     = (int*)   (ws + 71140000);       // 1,024
    int*    bscan    = (int*)   (ws + 71142048);       // 1,024
    int*    row_start= (int*)   (ws + 71144096);       // 200,064
    int*    cursor   = (int*)   (ws + 71344160);       // 200,000
    // path-specific region at 72 MB:
    uchar*  emb      = (uchar*) (ws + 72000000);       // 102.4 MB fp8 (emb path)
    float*  ea_s     = (float*) (ws + 72000000);       // 44.8 MB (fallback path)
    const bool use_emb = (ws_size >= (size_t)174400000);

    const int NB = (NN + 255) / 256;  // 196

    // --- CSR build (edge_index constant across layers) ---
    hipMemsetAsync(deg, 0, NN * sizeof(int), stream);
    hist_kernel<<<(NE + 255) / 256, 256, 0, stream>>>(edge_idx, deg);
    scan1_kernel<<<NB, 256, 0, stream>>>(deg, incl, bsum);
    scan2_kernel<<<1, 256, 0, stream>>>(bsum, bscan, NB);
    scan3_kernel<<<NB, 256, 0, stream>>>(deg, incl, bscan, row_start, cursor);
    scatter_kernel<<<(NE + 255) / 256, 256, 0, stream>>>(edge_idx, cursor, srcs, eid);

    if (use_emb) {
        embed_edges_kernel<<<NE / EB, 256, 0, stream>>>(
            edge_attr, eid, edge_W, edge_b, emb);
    } else {
        permute_ea_kernel<<<(NE * 7 + 255) / 256, 256, 0, stream>>>(edge_attr, eid, ea_s);
    }

    init_kernel<<<448 + (NN * 64 + 255) / 256, 256, 0, stream>>>(
        x, node_W, node_b, (const float*)d_in[8], (const float*)d_in[14],
        (const float*)d_in[16], h, hb, wb, projT);

    for (int i = 0; i < NL; ++i) {
        if (use_emb) {
            agg_emb_kernel<<<(NN + 3) / 4, 256, 0, stream>>>(
                h, hb, srcs, row_start, emb, zin);
        } else {
            agg_recompute_kernel<<<(NN + 3) / 4, 256, 0, stream>>>(
                h, hb, srcs, row_start, ea_s, edge_W, edge_b, zin);
        }
        fused_layer_kernel<<<(NN + 63) / 64, 256, 0, stream>>>(
            zin, wb + (size_t)i * HD * HD, lin1_b + i * HD,
            bn_gamma + i * HD, bn_beta + i * HD, bn_mean + i * HD, bn_var + i * HD,
            wb + (size_t)(3 + i) * HD * HD, lin2_b + i * HD,
            h, (ushort*)hb, NN);
    }

    hipMemsetAsync(pooled, 0, NG * HD * sizeof(float) + NG * sizeof(int) + 4000, stream);
    pool_kernel<<<(NN + 31) / 32, 128, 0, stream>>>(h, batch, pooled, counts, NN, 32);
    final_kernel<<<NG, HD, 0, stream>>>(pooled, counts, projT, proj_b, (float*)d_out);
}

// Round 11
// 443.836 us; speedup vs baseline: 1.3815x; 1.0614x over previous
//
#include <hip/hip_runtime.h>

typedef unsigned int uint;
typedef unsigned short ushort;
typedef __attribute__((ext_vector_type(8))) short bf16x8;
typedef __attribute__((ext_vector_type(4))) float f32x4;
typedef __attribute__((ext_vector_type(2))) _Float16 half2_t;

#define NN 50000
#define NE 800000
#define NG 64
#define NODE_F 11
#define EDGE_F 14
#define HD 128
#define NL 3
#define BN_EPS 1e-5f

#if defined(__has_builtin)
#if __has_builtin(__builtin_amdgcn_fdot2)
#define HAS_DOT2 1
#endif
#endif

__device__ __forceinline__ uint bfround(float v) {
    uint b = __float_as_uint(v);
    return (b + 0x7fffu + ((b >> 16) & 1u)) >> 16;
}

__device__ __forceinline__ float dot2f(half2_t a, half2_t b, float acc) {
#ifdef HAS_DOT2
    return __builtin_amdgcn_fdot2(a, b, acc, false);
#else
    return acc + (float)a[0] * (float)b[0] + (float)a[1] * (float)b[1];
#endif
}

__device__ __forceinline__ half2_t u2h2(uint u) {
    return __builtin_bit_cast(half2_t, u);
}

// ------- init: prep weights (blocks 0..447) + node embedding (rest) --------
__global__ __launch_bounds__(256)
void init_kernel(const float* __restrict__ x, const float* __restrict__ nW,
                 const float* __restrict__ nb_, const float* __restrict__ lin1,
                 const float* __restrict__ lin2, const float* __restrict__ proj,
                 float* __restrict__ h, uint* __restrict__ hb,
                 ushort* __restrict__ wb, float* __restrict__ projT)
{
    int bid = blockIdx.x;
    if (bid < 448) {
        int idx = bid * 256 + threadIdx.x;
        if (idx >= 7 * HD * HD) return;
        if (idx < 6 * HD * HD) {
            int m = idx >> 14, e = idx & (HD * HD - 1);
            const float* src = (m < 3) ? (lin1 + m * HD * HD) : (lin2 + (m - 3) * HD * HD);
            wb[idx] = (ushort)bfround(src[e]);
        } else {
            int e = idx - 6 * HD * HD;
            int r = e >> 7, c = e & 127;
            projT[c * HD + r] = proj[r * HD + c];
        }
    } else {
        int idx = (bid - 448) * 256 + threadIdx.x;
        if (idx >= NN * 64) return;
        int node = idx >> 6, cp = idx & 63;
        int c2 = cp * 2;
        const float* xr = x + node * NODE_F;
        const float* w0 = nW + c2 * NODE_F;
        const float* w1 = w0 + NODE_F;
        float a0 = nb_[c2], a1 = nb_[c2 + 1];
#pragma unroll
        for (int f = 0; f < NODE_F; ++f) { float xv = xr[f]; a0 += xv * w0[f]; a1 += xv * w1[f]; }
        *(float2*)&h[(size_t)node * HD + c2] = make_float2(a0, a1);
        hb[idx] = bfround(a0) | (bfround(a1) << 16);
    }
}

// ----------------------------- CSR construction ----------------------------
__global__ __launch_bounds__(256)
void hist_kernel(const int* __restrict__ ei, int* __restrict__ deg)
{
    int e = blockIdx.x * 256 + threadIdx.x;
    if (e < NE) atomicAdd(&deg[ei[NE + e]], 1);
}

__global__ __launch_bounds__(256)
void scan1_kernel(const int* __restrict__ deg, int* __restrict__ incl, int* __restrict__ bsum)
{
    int i = blockIdx.x * 256 + threadIdx.x;
    int v = (i < NN) ? deg[i] : 0;
    int lane = threadIdx.x & 63;
#pragma unroll
    for (int off = 1; off < 64; off <<= 1) {
        int u = __shfl_up(v, off);
        if (lane >= off) v += u;
    }
    __shared__ int wsum[4];
    if (lane == 63) wsum[threadIdx.x >> 6] = v;
    __syncthreads();
    int wid = threadIdx.x >> 6;
    int add = 0;
#pragma unroll
    for (int w = 0; w < 3; ++w) if (w < wid) add += wsum[w];
    v += add;
    if (i < NN) incl[i] = v;
    if (threadIdx.x == 255) bsum[blockIdx.x] = v;
}

__global__ __launch_bounds__(256)
void scan2_kernel(const int* __restrict__ bsum, int* __restrict__ bscan, int nb)
{
    int i = threadIdx.x;
    int v = (i < nb) ? bsum[i] : 0;
    int lane = i & 63;
#pragma unroll
    for (int off = 1; off < 64; off <<= 1) {
        int u = __shfl_up(v, off);
        if (lane >= off) v += u;
    }
    __shared__ int wsum[4];
    if (lane == 63) wsum[i >> 6] = v;
    __syncthreads();
    int wid = i >> 6;
    int add = 0;
#pragma unroll
    for (int w = 0; w < 3; ++w) if (w < wid) add += wsum[w];
    v += add;
    bscan[i] = v;
}

__global__ __launch_bounds__(256)
void scan3_kernel(const int* __restrict__ deg, const int* __restrict__ incl,
                  const int* __restrict__ bscan, int* __restrict__ row_start,
                  int* __restrict__ cursor)
{
    int i = blockIdx.x * 256 + threadIdx.x;
    if (i >= NN) return;
    int b = blockIdx.x;
    int base = (b > 0) ? bscan[b - 1] : 0;
    int rs = base + incl[i] - deg[i];
    row_start[i] = rs;
    cursor[i] = rs;
    if (i == 0) row_start[NN] = NE;
}

__global__ __launch_bounds__(256)
void scatter_kernel(const int* __restrict__ ei, int* __restrict__ cursor,
                    int* __restrict__ srcs, int* __restrict__ eid)
{
    int e = blockIdx.x * 256 + threadIdx.x;
    if (e >= NE) return;
    int s = ei[e], d = ei[NE + e];
    int pos = atomicAdd(&cursor[d], 1);
    srcs[pos] = s;
    eid[pos] = e;
}

// --- one-time: ea_h[j] = f16(edge_attr[eid[j]]), dst-sorted, 7 uints/edge ---
__global__ __launch_bounds__(256)
void permute_f16_kernel(const float* __restrict__ ea, const int* __restrict__ eid,
                        uint* __restrict__ ea_h)
{
    int idx = blockIdx.x * 256 + threadIdx.x;
    if (idx >= NE * 8) return;
    int el = idx >> 3, f2 = idx & 7;
    if (f2 >= 7) return;
    float2 v = *(const float2*)(ea + (size_t)eid[el] * EDGE_F + 2 * f2);
    half2_t hh;
    hh[0] = (_Float16)v.x;
    hh[1] = (_Float16)v.y;
    ea_h[(size_t)el * 7 + f2] = __builtin_bit_cast(uint, hh);
}

// --- agg: zin[n] = h[n] + sum_j relu(hb[src_j] + f16dot(ea_h[j], eW) + eb) --
// 1 wave/node, 2 ch/lane; weights as 14 half2 regs/lane; v_dot2_f32_f16.
#define EMSGH(HV, EP)                                                       \
    {                                                                       \
        float ax = bx, ay = by;                                             \
        _Pragma("unroll")                                                   \
        for (int f = 0; f < 7; ++f) {                                       \
            half2_t av = u2h2((EP)[f]);                                     \
            ax = dot2f(av, w0h[f], ax);                                     \
            ay = dot2f(av, w1h[f], ay);                                     \
        }                                                                   \
        float hx = __uint_as_float((HV) << 16);                             \
        float hy = __uint_as_float((HV) & 0xffff0000u);                     \
        accx += fmaxf(hx + ax, 0.f);                                        \
        accy += fmaxf(hy + ay, 0.f);                                        \
    }

__global__ __launch_bounds__(256)
void agg_f16_kernel(const float* __restrict__ h, const uint* __restrict__ hb,
                    const int* __restrict__ srcs, const int* __restrict__ row_start,
                    const uint* __restrict__ ea_h, const float* __restrict__ eW,
                    const float* __restrict__ eb, float* __restrict__ zin)
{
    int node = blockIdx.x * 4 + (threadIdx.x >> 6);
    if (node >= NN) return;
    int lane = threadIdx.x & 63;
    int c2 = lane * 2;
    // 28 consecutive weight floats per lane (rows c2, c2+1), 16B-aligned
    const float4* wp = (const float4*)(eW + lane * 28);
    float4 q0 = wp[0], q1 = wp[1], q2 = wp[2], q3 = wp[3], q4 = wp[4], q5 = wp[5], q6 = wp[6];
    float w0f[14], w1f[14];
    w0f[0]=q0.x; w0f[1]=q0.y; w0f[2]=q0.z; w0f[3]=q0.w;
    w0f[4]=q1.x; w0f[5]=q1.y; w0f[6]=q1.z; w0f[7]=q1.w;
    w0f[8]=q2.x; w0f[9]=q2.y; w0f[10]=q2.z; w0f[11]=q2.w;
    w0f[12]=q3.x; w0f[13]=q3.y;
    w1f[0]=q3.z; w1f[1]=q3.w;
    w1f[2]=q4.x; w1f[3]=q4.y; w1f[4]=q4.z; w1f[5]=q4.w;
    w1f[6]=q5.x; w1f[7]=q5.y; w1f[8]=q5.z; w1f[9]=q5.w;
    w1f[10]=q6.x; w1f[11]=q6.y; w1f[12]=q6.z; w1f[13]=q6.w;
    half2_t w0h[7], w1h[7];
#pragma unroll
    for (int f = 0; f < 7; ++f) {
        w0h[f][0] = (_Float16)w0f[2 * f]; w0h[f][1] = (_Float16)w0f[2 * f + 1];
        w1h[f][0] = (_Float16)w1f[2 * f]; w1h[f][1] = (_Float16)w1f[2 * f + 1];
    }
    float bx = eb[c2], by = eb[c2 + 1];
    float accx = 0.f, accy = 0.f;
    int beg = __builtin_amdgcn_readfirstlane(row_start[node]);
    int end = __builtin_amdgcn_readfirstlane(row_start[node + 1]);
    int j = beg;
    for (; j + 8 <= end; j += 8) {
        int s[8];
        uint hv[8];
#pragma unroll
        for (int q = 0; q < 8; ++q) s[q] = srcs[j + q];
#pragma unroll
        for (int q = 0; q < 8; ++q) hv[q] = hb[(size_t)s[q] * 64 + lane];
        const uint* e0 = ea_h + (size_t)j * 7;
        EMSGH(hv[0], e0);      EMSGH(hv[1], e0 + 7);
        EMSGH(hv[2], e0 + 14); EMSGH(hv[3], e0 + 21);
        EMSGH(hv[4], e0 + 28); EMSGH(hv[5], e0 + 35);
        EMSGH(hv[6], e0 + 42); EMSGH(hv[7], e0 + 49);
    }
    for (; j + 4 <= end; j += 4) {
        int s0 = srcs[j], s1 = srcs[j + 1], s2 = srcs[j + 2], s3 = srcs[j + 3];
        uint hv0 = hb[(size_t)s0 * 64 + lane];
        uint hv1 = hb[(size_t)s1 * 64 + lane];
        uint hv2 = hb[(size_t)s2 * 64 + lane];
        uint hv3 = hb[(size_t)s3 * 64 + lane];
        const uint* e0 = ea_h + (size_t)j * 7;
        EMSGH(hv0, e0);      EMSGH(hv1, e0 + 7);
        EMSGH(hv2, e0 + 14); EMSGH(hv3, e0 + 21);
    }
    for (; j < end; ++j) {
        uint hv0 = hb[(size_t)srcs[j] * 64 + lane];
        const uint* e0 = ea_h + (size_t)j * 7;
        EMSGH(hv0, e0);
    }
    float2 hn = *(const float2*)&h[(size_t)node * HD + c2];
    *(float2*)&zin[(size_t)node * HD + c2] = make_float2(hn.x + accx, hn.y + accy);
}

// --------- fused layer: h = relu(relu(BN(zin@W1^T+b1))@W2^T+b2) + h --------
__global__ __launch_bounds__(256)
void fused_layer_kernel(const float* __restrict__ zin,
                        const ushort* __restrict__ w1b, const float* __restrict__ b1,
                        const float* __restrict__ gamma, const float* __restrict__ beta,
                        const float* __restrict__ mean, const float* __restrict__ var,
                        const ushort* __restrict__ w2b, const float* __restrict__ b2,
                        float* __restrict__ h, ushort* __restrict__ hb, int n)
{
    __shared__ uint Ahi[64 * 64];  // bf16[64][128], XOR-swizzled; reused for z
    __shared__ uint Alo[64 * 64];
    const int t = threadIdx.x;
    const int nb = blockIdx.x * 64;

    {
        int row = t >> 2;
        int kq = (t & 3) * 32;
        int gn = nb + row;
        uint hiw[16], low[16];
        if (gn < n) {
            const float4* src = (const float4*)(zin + (size_t)gn * HD + kq);
#pragma unroll
            for (int i = 0; i < 8; ++i) {
                float4 v = src[i];
                uint h0 = bfround(v.x), h1 = bfround(v.y), h2 = bfround(v.z), h3 = bfround(v.w);
                float r0 = v.x - __uint_as_float(h0 << 16);
                float r1 = v.y - __uint_as_float(h1 << 16);
                float r2 = v.z - __uint_as_float(h2 << 16);
                float r3 = v.w - __uint_as_float(h3 << 16);
                hiw[2 * i]     = h0 | (h1 << 16);
                hiw[2 * i + 1] = h2 | (h3 << 16);
                low[2 * i]     = bfround(r0) | (bfround(r1) << 16);
                low[2 * i + 1] = bfround(r2) | (bfround(r3) << 16);
            }
        } else {
#pragma unroll
            for (int i = 0; i < 16; ++i) { hiw[i] = 0; low[i] = 0; }
        }
        uint rowbase = row * 256;
#pragma unroll
        for (int i = 0; i < 4; ++i) {
            uint byte = (rowbase + (kq + 8 * i) * 2) ^ ((row & 7) << 4);
            *(uint4*)((char*)Ahi + byte) = make_uint4(hiw[4 * i], hiw[4 * i + 1], hiw[4 * i + 2], hiw[4 * i + 3]);
            *(uint4*)((char*)Alo + byte) = make_uint4(low[4 * i], low[4 * i + 1], low[4 * i + 2], low[4 * i + 3]);
        }
    }

    const int w  = t >> 6, l = t & 63;
    const int lc = l & 15, lk = l >> 4;
    bf16x8 wf1[2][4], wf2[2][4];
#pragma unroll
    for (int ct = 0; ct < 2; ++ct)
#pragma unroll
        for (int ks = 0; ks < 4; ++ks) {
            size_t off = (size_t)(w * 32 + ct * 16 + lc) * HD + ks * 32 + lk * 8;
            wf1[ct][ks] = *(const bf16x8*)(w1b + off);
            wf2[ct][ks] = *(const bf16x8*)(w2b + off);
        }

    __syncthreads();

    f32x4 acc[4][2];
#pragma unroll
    for (int rt = 0; rt < 4; ++rt)
#pragma unroll
        for (int ct = 0; ct < 2; ++ct) acc[rt][ct] = (f32x4){0.f, 0.f, 0.f, 0.f};

#pragma unroll
    for (int ks = 0; ks < 4; ++ks) {
#pragma unroll
        for (int rt = 0; rt < 4; ++rt) {
            int row = rt * 16 + lc;
            uint byte = ((uint)(row * 256 + (ks * 32 + lk * 8) * 2)) ^ ((row & 7) << 4);
            bf16x8 ah = *(const bf16x8*)((char*)Ahi + byte);
            bf16x8 al = *(const bf16x8*)((char*)Alo + byte);
            acc[rt][0] = __builtin_amdgcn_mfma_f32_16x16x32_bf16(ah, wf1[0][ks], acc[rt][0], 0, 0, 0);
            acc[rt][0] = __builtin_amdgcn_mfma_f32_16x16x32_bf16(al, wf1[0][ks], acc[rt][0], 0, 0, 0);
            acc[rt][1] = __builtin_amdgcn_mfma_f32_16x16x32_bf16(ah, wf1[1][ks], acc[rt][1], 0, 0, 0);
            acc[rt][1] = __builtin_amdgcn_mfma_f32_16x16x32_bf16(al, wf1[1][ks], acc[rt][1], 0, 0, 0);
        }
    }

    __syncthreads();

#pragma unroll
    for (int ct = 0; ct < 2; ++ct) {
        int col = w * 32 + ct * 16 + lc;
        float bi = b1[col];
        float scv = gamma[col] * rsqrtf(var[col] + BN_EPS);
        float shv = beta[col] - mean[col] * scv;
#pragma unroll
        for (int rt = 0; rt < 4; ++rt) {
#pragma unroll
            for (int r = 0; r < 4; ++r) {
                int rowl = rt * 16 + lk * 4 + r;
                float v = (acc[rt][ct][r] + bi) * scv + shv;
                v = fmaxf(v, 0.f);
                uint byte = ((uint)(rowl * 256 + col * 2)) ^ ((rowl & 7) << 4);
                *(ushort*)((char*)Ahi + byte) = (ushort)bfround(v);
            }
        }
    }

    __syncthreads();

    f32x4 acc2[4][2];
#pragma unroll
    for (int rt = 0; rt < 4; ++rt)
#pragma unroll
        for (int ct = 0; ct < 2; ++ct) acc2[rt][ct] = (f32x4){0.f, 0.f, 0.f, 0.f};

#pragma unroll
    for (int ks = 0; ks < 4; ++ks) {
#pragma unroll
        for (int rt = 0; rt < 4; ++rt) {
            int row = rt * 16 + lc;
            uint byte = ((uint)(row * 256 + (ks * 32 + lk * 8) * 2)) ^ ((row & 7) << 4);
            bf16x8 az = *(const bf16x8*)((char*)Ahi + byte);
            acc2[rt][0] = __builtin_amdgcn_mfma_f32_16x16x32_bf16(az, wf2[0][ks], acc2[rt][0], 0, 0, 0);
            acc2[rt][1] = __builtin_amdgcn_mfma_f32_16x16x32_bf16(az, wf2[1][ks], acc2[rt][1], 0, 0, 0);
        }
    }

#pragma unroll
    for (int ct = 0; ct < 2; ++ct) {
        int col = w * 32 + ct * 16 + lc;
        float bi = b2[col];
#pragma unroll
        for (int rt = 0; rt < 4; ++rt) {
#pragma unroll
            for (int r = 0; r < 4; ++r) {
                int row = nb + rt * 16 + lk * 4 + r;
                if (row < n) {
                    float v = fmaxf(acc2[rt][ct][r] + bi, 0.f) + h[(size_t)row * HD + col];
                    h[(size_t)row * HD + col] = v;
                    hb[(size_t)row * HD + col] = (ushort)bfround(v);
                }
            }
        }
    }
}

// -------- pooling: sorted batch_idx -> chunked local sums, rare atomics ----
__global__ __launch_bounds__(128)
void pool_kernel(const float* __restrict__ h, const int* __restrict__ batch,
                 float* __restrict__ pooled, int* __restrict__ counts, int n, int chunk)
{
    int c = threadIdx.x;
    int n_start = blockIdx.x * chunk;
    if (n_start >= n) return;
    int n_end = min(n_start + chunk, n);
    float local = 0.f;
    int cnt = 0;
    int g_cur = batch[n_start];
    for (int nd = n_start; nd < n_end; ++nd) {
        int g = batch[nd];
        if (g != g_cur) {
            atomicAdd(&pooled[g_cur * HD + c], local);
            if (c == 0) atomicAdd(&counts[g_cur], cnt);
            local = 0.f; cnt = 0; g_cur = g;
        }
        local += h[(size_t)nd * HD + c];
        cnt++;
    }
    atomicAdd(&pooled[g_cur * HD + c], local);
    if (c == 0) atomicAdd(&counts[g_cur], cnt);
}

__global__ __launch_bounds__(128)
void final_kernel(const float* __restrict__ pooled, const int* __restrict__ counts,
                  const float* __restrict__ projT, const float* __restrict__ pb,
                  float* __restrict__ out)
{
    __shared__ float p_lds[HD];
    int g = blockIdx.x, p = threadIdx.x;
    float inv = 1.f / fmaxf((float)counts[g], 1.f);
    p_lds[p] = pooled[g * HD + p];
    __syncthreads();
    float acc = 0.f;
#pragma unroll 4
    for (int c = 0; c < HD; ++c) acc += p_lds[c] * projT[c * HD + p];
    out[g * HD + p] = acc * inv + pb[p];
}

extern "C" void kernel_launch(void* const* d_in, const int* in_sizes, int n_in,
                              void* d_out, int out_size, void* d_ws, size_t ws_size,
                              hipStream_t stream)
{
    const float* x        = (const float*)d_in[0];
    const int*   edge_idx = (const int*)d_in[1];
    const float* edge_attr= (const float*)d_in[2];
    const int*   batch    = (const int*)d_in[3];
    const float* node_W   = (const float*)d_in[4];
    const float* node_b   = (const float*)d_in[5];
    const float* edge_W   = (const float*)d_in[6];
    const float* edge_b   = (const float*)d_in[7];
    const float* lin1_b   = (const float*)d_in[9];
    const float* bn_gamma = (const float*)d_in[10];
    const float* bn_beta  = (const float*)d_in[11];
    const float* bn_mean  = (const float*)d_in[12];
    const float* bn_var   = (const float*)d_in[13];
    const float* lin2_b   = (const float*)d_in[15];
    const float* proj_b   = (const float*)d_in[17];

    char* ws = (char*)d_ws;
    float*  h        = (float*) (ws);                  // 25.6 MB
    float*  zin      = (float*) (ws + 25600000);       // 25.6 MB
    uint*   hb       = (uint*)  (ws + 51200000);       // 12.8 MB (packed bf16, 2ch/uint)
    int*    srcs     = (int*)   (ws + 64000000);       // 3.2 MB
    int*    eid      = (int*)   (ws + 67200000);       // 3.2 MB
    ushort* wb       = (ushort*)(ws + 70400000);       // 196,608
    float*  projT    = (float*) (ws + 70600000);       // 65,536
    float*  pooled   = (float*) (ws + 70700000);       // 32,768
    int*    counts   = (int*)   (ws + 70732768);       // 256 (contiguous after pooled)
    int*    deg      = (int*)   (ws + 70740000);       // 200,000
    int*    incl     = (int*)   (ws + 70940000);       // 200,000
    int*    bsum     = (int*)   (ws + 71140000);       // 1,024
    int*    bscan    = (int*)   (ws + 71142048);       // 1,024
    int*    row_start= (int*)   (ws + 71144096);       // 200,064
    int*    cursor   = (int*)   (ws + 71344160);       // 200,000
    uint*   ea_h     = (uint*)  (ws + 72000000);       // 22.4 MB (f16 edge feats, dst-sorted)

    const int NB = (NN + 255) / 256;  // 196

    // --- CSR build (edge_index constant across layers) ---
    hipMemsetAsync(deg, 0, NN * sizeof(int), stream);
    hist_kernel<<<(NE + 255) / 256, 256, 0, stream>>>(edge_idx, deg);
    scan1_kernel<<<NB, 256, 0, stream>>>(deg, incl, bsum);
    scan2_kernel<<<1, 256, 0, stream>>>(bsum, bscan, NB);
    scan3_kernel<<<NB, 256, 0, stream>>>(deg, incl, bscan, row_start, cursor);
    scatter_kernel<<<(NE + 255) / 256, 256, 0, stream>>>(edge_idx, cursor, srcs, eid);
    permute_f16_kernel<<<(NE * 8 + 255) / 256, 256, 0, stream>>>(edge_attr, eid, ea_h);

    init_kernel<<<448 + (NN * 64 + 255) / 256, 256, 0, stream>>>(
        x, node_W, node_b, (const float*)d_in[8], (const float*)d_in[14],
        (const float*)d_in[16], h, hb, wb, projT);

    for (int i = 0; i < NL; ++i) {
        agg_f16_kernel<<<(NN + 3) / 4, 256, 0, stream>>>(
            h, hb, srcs, row_start, ea_h, edge_W, edge_b, zin);
        fused_layer_kernel<<<(NN + 63) / 64, 256, 0, stream>>>(
            zin, wb + (size_t)i * HD * HD, lin1_b + i * HD,
            bn_gamma + i * HD, bn_beta + i * HD, bn_mean + i * HD, bn_var + i * HD,
            wb + (size_t)(3 + i) * HD * HD, lin2_b + i * HD,
            h, (ushort*)hb, NN);
    }

    hipMemsetAsync(pooled, 0, NG * HD * sizeof(float) + NG * sizeof(int) + 4000, stream);
    pool_kernel<<<(NN + 31) / 32, 128, 0, stream>>>(h, batch, pooled, counts, NN, 32);
    final_kernel<<<NG, HD, 0, stream>>>(pooled, counts, projT, proj_b, (float*)d_out);
}